// Round 1
// baseline (3351.059 us; speedup 1.0000x reference)
//
#include <hip/hip_runtime.h>
#include <hip/hip_bf16.h>

#define BATCH 2
#define NTOK  32768
#define CH    256
#define NH    8
#define HDIM  32
#define NG    32
#define NSC   64
#define NDC   32

// ---------------------------------------------------------------------------
// Kernel 1: LN1 + dual GEMM (x@Wfx | x@Wx) + slice softmax.
// 16 tokens/block, 256 threads. Writes fxm (bf16, [tok][h*32+d]) and
// sw (bf16, [tok][h*32+g]).
// ---------------------------------------------------------------------------
__global__ __launch_bounds__(256) void k1_ln_gemm_slice(
    const float* __restrict__ fx,
    const float* __restrict__ g1, const float* __restrict__ b1,
    const float* __restrict__ Wfx, const float* __restrict__ bfx,
    const float* __restrict__ Wx,  const float* __restrict__ bx,
    const float* __restrict__ Wsl, const float* __restrict__ bsl,
    const float* __restrict__ temp,
    __hip_bfloat16* __restrict__ fxm_o, __hip_bfloat16* __restrict__ sw_o)
{
    __shared__ float xs[16][CH];    // 16KB LN'ed input
    __shared__ float os[16][512];   // 32KB [fxm | xm]
    const int tid = threadIdx.x;
    const long tok0 = (long)blockIdx.x * 16;
    const int lane = tid & 63, wv = tid >> 6;

    // ---- LN1: each wave handles 4 tokens ----
    #pragma unroll
    for (int tt = 0; tt < 4; ++tt) {
        const int t = wv * 4 + tt;
        const float* row = fx + (tok0 + t) * CH;
        float v[4];
        float s = 0.f, s2 = 0.f;
        #pragma unroll
        for (int j = 0; j < 4; ++j) {
            v[j] = row[lane + 64 * j];
            s += v[j]; s2 += v[j] * v[j];
        }
        #pragma unroll
        for (int off = 32; off; off >>= 1) {
            s  += __shfl_xor(s,  off);
            s2 += __shfl_xor(s2, off);
        }
        const float mean = s * (1.f / CH);
        const float rs = rsqrtf(s2 * (1.f / CH) - mean * mean + 1e-5f);
        #pragma unroll
        for (int j = 0; j < 4; ++j) {
            const int c = lane + 64 * j;
            xs[t][c] = (v[j] - mean) * rs * g1[c] + b1[c];
        }
    }
    __syncthreads();

    // ---- dual GEMM: out(16x512) = xs(16x256) @ [Wfx | Wx] ----
    const int tx = tid & 63, ty = tid >> 6;
    const float* W    = (tx < 32) ? Wfx : Wx;
    const float* bias = (tx < 32) ? bfx : bx;
    const int cb = (tx & 31) * 8;
    float acc[4][8];
    #pragma unroll
    for (int i = 0; i < 4; ++i)
        #pragma unroll
        for (int j = 0; j < 8; ++j) acc[i][j] = 0.f;

    #pragma unroll 4
    for (int k = 0; k < CH; ++k) {
        const float a0 = xs[ty * 4 + 0][k];
        const float a1 = xs[ty * 4 + 1][k];
        const float a2 = xs[ty * 4 + 2][k];
        const float a3 = xs[ty * 4 + 3][k];
        const float4 w0 = *reinterpret_cast<const float4*>(W + (long)k * 256 + cb);
        const float4 w1 = *reinterpret_cast<const float4*>(W + (long)k * 256 + cb + 4);
        const float wreg[8] = {w0.x, w0.y, w0.z, w0.w, w1.x, w1.y, w1.z, w1.w};
        #pragma unroll
        for (int j = 0; j < 8; ++j) {
            acc[0][j] += a0 * wreg[j];
            acc[1][j] += a1 * wreg[j];
            acc[2][j] += a2 * wreg[j];
            acc[3][j] += a3 * wreg[j];
        }
    }
    const int ocb = (tx < 32) ? cb : (256 + cb);
    #pragma unroll
    for (int i = 0; i < 4; ++i)
        #pragma unroll
        for (int j = 0; j < 8; ++j)
            os[ty * 4 + i][ocb + j] = acc[i][j] + bias[cb + j];
    __syncthreads();

    // ---- slice softmax: 128 threads, one (token, head) each ----
    if (tid < 128) {
        const int t = tid >> 3, h = tid & 7;
        const float* xm = &os[t][256 + h * 32];
        const float it = 1.f / temp[h];
        float lg[32];
        float mx = -1e30f;
        #pragma unroll
        for (int g = 0; g < 32; ++g) {
            float a = bsl[g];
            #pragma unroll
            for (int d = 0; d < 32; ++d) a += xm[d] * Wsl[d * 32 + g];
            a *= it;
            lg[g] = a;
            mx = fmaxf(mx, a);
        }
        float ssum = 0.f;
        #pragma unroll
        for (int g = 0; g < 32; ++g) { lg[g] = expf(lg[g] - mx); ssum += lg[g]; }
        const float inv = 1.f / ssum;
        __hip_bfloat16* swp = sw_o + (tok0 + t) * 256 + h * 32;
        #pragma unroll
        for (int g = 0; g < 32; ++g) swp[g] = __float2bfloat16(lg[g] * inv);
    }

    // ---- store fxm as bf16 (all threads) ----
    for (int idx = tid; idx < 16 * 256; idx += 256) {
        const int t = idx >> 8, c = idx & 255;
        fxm_o[(tok0 + t) * 256 + c] = __float2bfloat16(os[t][c]);
    }
}

// ---------------------------------------------------------------------------
// Kernel 2: st partials. grid = (B*H)*16 chunks; each block reduces 2048
// tokens of one (b,h) into pst[block][32*32] and pn[block][32]. Deterministic.
// ---------------------------------------------------------------------------
__global__ __launch_bounds__(256) void k2_st_partial(
    const __hip_bfloat16* __restrict__ fxm, const __hip_bfloat16* __restrict__ sw,
    float* __restrict__ pst, float* __restrict__ pn)
{
    __shared__ float fl[8][32];
    __shared__ float sl[8][32];
    const int tid = threadIdx.x;
    const int blk = blockIdx.x;             // bh*16 + chunk
    const int bh = blk >> 4, chunk = blk & 15;
    const int b = bh >> 3, h = bh & 7;
    const long nbase = (long)b * NTOK + (long)chunk * 2048;
    const int g = tid >> 3, dq = tid & 7, db = dq * 4;
    const int tl = tid >> 5, jj = tid & 31;
    float a0 = 0.f, a1 = 0.f, a2 = 0.f, a3 = 0.f, nacc = 0.f;

    for (int nb = 0; nb < 2048; nb += 8) {
        const long base = (nbase + nb + tl) * 256 + h * 32 + jj;
        fl[tl][jj] = __bfloat162float(fxm[base]);
        sl[tl][jj] = __bfloat162float(sw[base]);
        __syncthreads();
        #pragma unroll
        for (int t = 0; t < 8; ++t) {
            const float s = sl[t][g];
            if (dq == 0) nacc += s;
            a0 += s * fl[t][db + 0];
            a1 += s * fl[t][db + 1];
            a2 += s * fl[t][db + 2];
            a3 += s * fl[t][db + 3];
        }
        __syncthreads();
    }
    float* o = pst + (long)blk * 1024 + g * 32 + db;
    o[0] = a0; o[1] = a1; o[2] = a2; o[3] = a3;
    if (dq == 0) pn[blk * 32 + g] = nacc;
}

// ---------------------------------------------------------------------------
// Kernel 3: reduce partials -> st; tiny slice self-attn + cross-attn -> ost.
// 16 blocks (one per b,h), 256 threads, all f32 in LDS.
// ---------------------------------------------------------------------------
__global__ __launch_bounds__(256) void k3_slice_attn(
    const float* __restrict__ pst, const float* __restrict__ pn,
    const float* __restrict__ ctx,
    const float* __restrict__ Wq, const float* __restrict__ Wk, const float* __restrict__ Wv,
    const float* __restrict__ Wcq, const float* __restrict__ bcq,
    const float* __restrict__ Wck, const float* __restrict__ bck,
    const float* __restrict__ Wcv, const float* __restrict__ bcv,
    const float* __restrict__ mix, float* __restrict__ ost_o)
{
    __shared__ float st[1024], qm[1024], km[1024], vm[1024], cqm[1024];
    __shared__ float ckm[2048], cvm[2048], attn[2048], stok[1024], nb[32];
    const int tid = threadIdx.x;
    const int bh = blockIdx.x;

    if (tid < 32) {
        float s = 0.f;
        for (int c = 0; c < 16; ++c) s += pn[(bh * 16 + c) * 32 + tid];
        nb[tid] = s;
    }
    __syncthreads();
    for (int i = tid; i < 1024; i += 256) {
        float s = 0.f;
        for (int c = 0; c < 16; ++c) s += pst[(long)(bh * 16 + c) * 1024 + i];
        st[i] = s / (nb[i >> 5] + 1e-5f);
    }
    __syncthreads();

    for (int i = tid; i < 1024; i += 256) {
        const int g = i >> 5, d = i & 31;
        float aq = 0.f, ak = 0.f, av = 0.f, ac = bcq[d];
        #pragma unroll
        for (int e = 0; e < 32; ++e) {
            const float s = st[g * 32 + e];
            aq += s * Wq[e * 32 + d];
            ak += s * Wk[e * 32 + d];
            av += s * Wv[e * 32 + d];
            ac += s * Wcq[e * 32 + d];
        }
        qm[i] = aq; km[i] = ak; vm[i] = av; cqm[i] = ac;
    }
    const float* cbp = ctx + (long)bh * (NSC * NDC);
    for (int i = tid; i < 2048; i += 256) {
        const int s_ = i >> 5, d = i & 31;
        float w1 = bck[d], w2 = bcv[d];
        #pragma unroll
        for (int e = 0; e < 32; ++e) {
            const float cval = cbp[s_ * 32 + e];
            w1 += cval * Wck[e * 32 + d];
            w2 += cval * Wcv[e * 32 + d];
        }
        ckm[i] = w1; cvm[i] = w2;
    }
    __syncthreads();

    const float scale = 0.17677669529663687f;  // 32^-0.5
    for (int i = tid; i < 1024; i += 256) {
        const int g = i >> 5, m = i & 31;
        float a = 0.f;
        #pragma unroll
        for (int d = 0; d < 32; ++d) a += qm[g * 32 + d] * km[m * 32 + d];
        attn[i] = a * scale;
    }
    __syncthreads();
    if (tid < 32) {
        float mx = -1e30f;
        for (int m = 0; m < 32; ++m) mx = fmaxf(mx, attn[tid * 32 + m]);
        float s = 0.f;
        for (int m = 0; m < 32; ++m) { const float e = expf(attn[tid * 32 + m] - mx); attn[tid * 32 + m] = e; s += e; }
        const float inv = 1.f / s;
        for (int m = 0; m < 32; ++m) attn[tid * 32 + m] *= inv;
    }
    __syncthreads();
    for (int i = tid; i < 1024; i += 256) {
        const int g = i >> 5, d = i & 31;
        float a = 0.f;
        #pragma unroll
        for (int m = 0; m < 32; ++m) a += attn[g * 32 + m] * vm[m * 32 + d];
        stok[i] = a;
    }
    __syncthreads();
    for (int i = tid; i < 2048; i += 256) {
        const int g = i >> 6, s_ = i & 63;
        float a = 0.f;
        #pragma unroll
        for (int d = 0; d < 32; ++d) a += cqm[g * 32 + d] * ckm[s_ * 32 + d];
        attn[i] = a * scale;
    }
    __syncthreads();
    if (tid < 32) {
        float mx = -1e30f;
        for (int m = 0; m < 64; ++m) mx = fmaxf(mx, attn[tid * 64 + m]);
        float s = 0.f;
        for (int m = 0; m < 64; ++m) { const float e = expf(attn[tid * 64 + m] - mx); attn[tid * 64 + m] = e; s += e; }
        const float inv = 1.f / s;
        for (int m = 0; m < 64; ++m) attn[tid * 64 + m] *= inv;
    }
    __syncthreads();
    const float mw = 1.f / (1.f + expf(-mix[0]));
    for (int i = tid; i < 1024; i += 256) {
        const int g = i >> 5, d = i & 31;
        float a = 0.f;
        #pragma unroll
        for (int s_ = 0; s_ < 64; ++s_) a += attn[g * 64 + s_] * cvm[s_ * 32 + d];
        ost_o[(long)bh * 1024 + i] = mw * stok[i] + (1.f - mw) * a;
    }
}

// ---------------------------------------------------------------------------
// Kernel 4: de-slice (sw @ ost) + Wout GEMM + bout + fx residual -> d_out.
// 16 tokens/block, 256 threads.
// ---------------------------------------------------------------------------
__global__ __launch_bounds__(256) void k4_deslice_out(
    const __hip_bfloat16* __restrict__ sw, const float* __restrict__ ost,
    const float* __restrict__ Wout, const float* __restrict__ bout,
    const float* __restrict__ fx, float* __restrict__ out)
{
    __shared__ float ol[8192];                 // 32KB  ost for this batch
    __shared__ float al[16][256];              // 16KB  de-sliced tokens
    __shared__ __hip_bfloat16 swl[16 * 256];   // 8KB
    const int tid = threadIdx.x;
    const long tok0 = (long)blockIdx.x * 16;
    const int b = (int)(tok0 >> 15);

    for (int i = tid; i < 8192; i += 256) ol[i] = ost[b * 8192 + i];
    for (int i = tid; i < 4096; i += 256) swl[i] = sw[tok0 * 256 + i];
    __syncthreads();

    for (int i = tid; i < 4096; i += 256) {
        const int t = i >> 8, c = i & 255;
        const int h = c >> 5, d = c & 31;
        const __hip_bfloat16* swr = &swl[t * 256 + h * 32];
        const float* op = &ol[h * 1024 + d];
        float a = 0.f;
        #pragma unroll
        for (int g = 0; g < 32; ++g) a += __bfloat162float(swr[g]) * op[g * 32];
        al[t][c] = a;
    }
    __syncthreads();

    const int tx = tid & 63, ty = tid >> 6;
    const int cb = tx * 4;
    float acc[4][4];
    #pragma unroll
    for (int i = 0; i < 4; ++i)
        #pragma unroll
        for (int j = 0; j < 4; ++j) acc[i][j] = 0.f;

    #pragma unroll 4
    for (int k = 0; k < 256; ++k) {
        const float4 w = *reinterpret_cast<const float4*>(Wout + (long)k * 256 + cb);
        #pragma unroll
        for (int i = 0; i < 4; ++i) {
            const float a = al[ty * 4 + i][k];
            acc[i][0] += a * w.x; acc[i][1] += a * w.y;
            acc[i][2] += a * w.z; acc[i][3] += a * w.w;
        }
    }
    const float4 bo = *reinterpret_cast<const float4*>(bout + cb);
    #pragma unroll
    for (int i = 0; i < 4; ++i) {
        const long r = (tok0 + ty * 4 + i) * 256 + cb;
        const float4 f = *reinterpret_cast<const float4*>(fx + r);
        float4 o;
        o.x = acc[i][0] + bo.x + f.x;
        o.y = acc[i][1] + bo.y + f.y;
        o.z = acc[i][2] + bo.z + f.z;
        o.w = acc[i][3] + bo.w + f.w;
        *reinterpret_cast<float4*>(out + r) = o;
    }
}

// ---------------------------------------------------------------------------
// Kernel 5: MLP: LN2 -> @Wm1 -> exact GELU -> @Wm2 -> residual, in-place on out.
// 8 tokens/block, 256 threads.
// ---------------------------------------------------------------------------
__global__ __launch_bounds__(256) void k5_mlp(
    float* __restrict__ io,
    const float* __restrict__ g2, const float* __restrict__ b2,
    const float* __restrict__ Wm1, const float* __restrict__ bm1,
    const float* __restrict__ Wm2, const float* __restrict__ bm2)
{
    __shared__ float xs[8][256];    // raw fx1 (residual)
    __shared__ float hs[8][256];    // LN2 output
    __shared__ float ms[8][1024];   // gelu(h@Wm1+b)
    const int tid = threadIdx.x;
    const long tok0 = (long)blockIdx.x * 8;
    const int lane = tid & 63, wv = tid >> 6;

    #pragma unroll
    for (int tt = 0; tt < 2; ++tt) {
        const int t = wv * 2 + tt;
        const float* row = io + (tok0 + t) * 256;
        float v[4];
        float s = 0.f, s2 = 0.f;
        #pragma unroll
        for (int j = 0; j < 4; ++j) {
            v[j] = row[lane + 64 * j];
            s += v[j]; s2 += v[j] * v[j];
        }
        #pragma unroll
        for (int off = 32; off; off >>= 1) {
            s  += __shfl_xor(s,  off);
            s2 += __shfl_xor(s2, off);
        }
        const float mean = s * (1.f / 256.f);
        const float rs = rsqrtf(s2 * (1.f / 256.f) - mean * mean + 1e-5f);
        #pragma unroll
        for (int j = 0; j < 4; ++j) {
            const int c = lane + 64 * j;
            xs[t][c] = v[j];
            hs[t][c] = (v[j] - mean) * rs * g2[c] + b2[c];
        }
    }
    __syncthreads();

    const int tx = tid & 63, ty = tid >> 6;
    {   // GEMM1: 8x1024, K=256
        const int cb = tx * 16;
        float acc[2][16];
        #pragma unroll
        for (int i = 0; i < 2; ++i)
            #pragma unroll
            for (int j = 0; j < 16; ++j) acc[i][j] = 0.f;

        #pragma unroll 2
        for (int k = 0; k < 256; ++k) {
            const float a0 = hs[ty * 2 + 0][k];
            const float a1 = hs[ty * 2 + 1][k];
            const float4* wp = reinterpret_cast<const float4*>(Wm1 + (long)k * 1024 + cb);
            #pragma unroll
            for (int q = 0; q < 4; ++q) {
                const float4 w = wp[q];
                acc[0][q * 4 + 0] += a0 * w.x; acc[0][q * 4 + 1] += a0 * w.y;
                acc[0][q * 4 + 2] += a0 * w.z; acc[0][q * 4 + 3] += a0 * w.w;
                acc[1][q * 4 + 0] += a1 * w.x; acc[1][q * 4 + 1] += a1 * w.y;
                acc[1][q * 4 + 2] += a1 * w.z; acc[1][q * 4 + 3] += a1 * w.w;
            }
        }
        #pragma unroll
        for (int i = 0; i < 2; ++i)
            #pragma unroll
            for (int j = 0; j < 16; ++j) {
                float m = acc[i][j] + bm1[cb + j];
                m = 0.5f * m * (1.f + erff(m * 0.70710678118f));
                ms[ty * 2 + i][cb + j] = m;
            }
    }
    __syncthreads();

    {   // GEMM2: 8x256, K=1024
        const int cb = tx * 4;
        float acc[2][4];
        #pragma unroll
        for (int i = 0; i < 2; ++i)
            #pragma unroll
            for (int j = 0; j < 4; ++j) acc[i][j] = 0.f;

        #pragma unroll 4
        for (int k = 0; k < 1024; ++k) {
            const float4 w = *reinterpret_cast<const float4*>(Wm2 + (long)k * 256 + cb);
            const float a0 = ms[ty * 2 + 0][k];
            const float a1 = ms[ty * 2 + 1][k];
            acc[0][0] += a0 * w.x; acc[0][1] += a0 * w.y; acc[0][2] += a0 * w.z; acc[0][3] += a0 * w.w;
            acc[1][0] += a1 * w.x; acc[1][1] += a1 * w.y; acc[1][2] += a1 * w.z; acc[1][3] += a1 * w.w;
        }
        const float4 bo = *reinterpret_cast<const float4*>(bm2 + cb);
        #pragma unroll
        for (int i = 0; i < 2; ++i) {
            const int t = ty * 2 + i;
            const long r = (tok0 + t) * 256 + cb;
            float4 o;
            o.x = xs[t][cb + 0] + acc[i][0] + bo.x;
            o.y = xs[t][cb + 1] + acc[i][1] + bo.y;
            o.z = xs[t][cb + 2] + acc[i][2] + bo.z;
            o.w = xs[t][cb + 3] + acc[i][3] + bo.w;
            *reinterpret_cast<float4*>(io + r) = o;
        }
    }
}

// ---------------------------------------------------------------------------
extern "C" void kernel_launch(void* const* d_in, const int* in_sizes, int n_in,
                              void* d_out, int out_size, void* d_ws, size_t ws_size,
                              hipStream_t stream)
{
    const float* fx   = (const float*)d_in[0];
    const float* ctx  = (const float*)d_in[1];
    const float* g1   = (const float*)d_in[2];
    const float* b1   = (const float*)d_in[3];
    const float* Wfx  = (const float*)d_in[4];
    const float* bfx  = (const float*)d_in[5];
    const float* Wx   = (const float*)d_in[6];
    const float* bx   = (const float*)d_in[7];
    const float* Wsl  = (const float*)d_in[8];
    const float* bsl  = (const float*)d_in[9];
    const float* temp = (const float*)d_in[10];
    const float* Wq   = (const float*)d_in[11];
    const float* Wk   = (const float*)d_in[12];
    const float* Wv   = (const float*)d_in[13];
    const float* Wcq  = (const float*)d_in[14];
    const float* bcq  = (const float*)d_in[15];
    const float* Wck  = (const float*)d_in[16];
    const float* bck  = (const float*)d_in[17];
    const float* Wcv  = (const float*)d_in[18];
    const float* bcv  = (const float*)d_in[19];
    const float* mix  = (const float*)d_in[20];
    const float* Wout = (const float*)d_in[21];
    const float* bout = (const float*)d_in[22];
    const float* g2   = (const float*)d_in[23];
    const float* b2   = (const float*)d_in[24];
    const float* Wm1  = (const float*)d_in[25];
    const float* bm1  = (const float*)d_in[26];
    const float* Wm2  = (const float*)d_in[27];
    const float* bm2  = (const float*)d_in[28];
    float* out = (float*)d_out;

    char* ws = (char*)d_ws;
    __hip_bfloat16* fxm = (__hip_bfloat16*)ws;                          // 32MB
    __hip_bfloat16* sw  = (__hip_bfloat16*)(ws + (size_t)33554432);     // 32MB
    float* pst = (float*)(ws + (size_t)67108864);                       // 1MB
    float* pn  = (float*)(ws + (size_t)67108864 + 1048576);             // 32KB
    float* ost = (float*)(ws + (size_t)67108864 + 1048576 + 32768);     // 64KB

    k1_ln_gemm_slice<<<4096, 256, 0, stream>>>(fx, g1, b1, Wfx, bfx, Wx, bx,
                                               Wsl, bsl, temp, fxm, sw);
    k2_st_partial<<<256, 256, 0, stream>>>(fxm, sw, pst, pn);
    k3_slice_attn<<<16, 256, 0, stream>>>(pst, pn, ctx, Wq, Wk, Wv,
                                          Wcq, bcq, Wck, bck, Wcv, bcv, mix, ost);
    k4_deslice_out<<<4096, 256, 0, stream>>>(sw, ost, Wout, bout, fx, out);
    k5_mlp<<<8192, 256, 0, stream>>>(out, g2, b2, Wm1, bm1, Wm2, bm2);
}

// Round 2
// 848.061 us; speedup vs baseline: 3.9514x; 3.9514x over previous
//
#include <hip/hip_runtime.h>
#include <hip/hip_bf16.h>

#define BATCH 2
#define NTOK  32768
#define CH    256
#define NH    8
#define HDIM  32
#define NG    32
#define NSC   64
#define NDC   32

typedef __attribute__((ext_vector_type(8))) short short8v;
typedef __attribute__((ext_vector_type(4))) short short4v;
typedef __attribute__((ext_vector_type(4))) float f32x4;

static __device__ __forceinline__ short f2bf(float f) {
    __hip_bfloat16 h = __float2bfloat16(f);
    return __builtin_bit_cast(short, h);
}

// ---------------------------------------------------------------------------
// Kernel 1: LN1 + dual GEMM (x@Wfx | x@Wx) + slice softmax.
// ---------------------------------------------------------------------------
__global__ __launch_bounds__(256) void k1_ln_gemm_slice(
    const float* __restrict__ fx,
    const float* __restrict__ g1, const float* __restrict__ b1,
    const float* __restrict__ Wfx, const float* __restrict__ bfx,
    const float* __restrict__ Wx,  const float* __restrict__ bx,
    const float* __restrict__ Wsl, const float* __restrict__ bsl,
    const float* __restrict__ temp,
    __hip_bfloat16* __restrict__ fxm_o, __hip_bfloat16* __restrict__ sw_o)
{
    __shared__ float xs[16][CH];
    __shared__ float os[16][512];
    const int tid = threadIdx.x;
    const long tok0 = (long)blockIdx.x * 16;
    const int lane = tid & 63, wv = tid >> 6;

    #pragma unroll
    for (int tt = 0; tt < 4; ++tt) {
        const int t = wv * 4 + tt;
        const float* row = fx + (tok0 + t) * CH;
        float v[4];
        float s = 0.f, s2 = 0.f;
        #pragma unroll
        for (int j = 0; j < 4; ++j) {
            v[j] = row[lane + 64 * j];
            s += v[j]; s2 += v[j] * v[j];
        }
        #pragma unroll
        for (int off = 32; off; off >>= 1) {
            s  += __shfl_xor(s,  off);
            s2 += __shfl_xor(s2, off);
        }
        const float mean = s * (1.f / CH);
        const float rs = rsqrtf(s2 * (1.f / CH) - mean * mean + 1e-5f);
        #pragma unroll
        for (int j = 0; j < 4; ++j) {
            const int c = lane + 64 * j;
            xs[t][c] = (v[j] - mean) * rs * g1[c] + b1[c];
        }
    }
    __syncthreads();

    const int tx = tid & 63, ty = tid >> 6;
    const float* W    = (tx < 32) ? Wfx : Wx;
    const float* bias = (tx < 32) ? bfx : bx;
    const int cb = (tx & 31) * 8;
    float acc[4][8];
    #pragma unroll
    for (int i = 0; i < 4; ++i)
        #pragma unroll
        for (int j = 0; j < 8; ++j) acc[i][j] = 0.f;

    #pragma unroll 4
    for (int k = 0; k < CH; ++k) {
        const float a0 = xs[ty * 4 + 0][k];
        const float a1 = xs[ty * 4 + 1][k];
        const float a2 = xs[ty * 4 + 2][k];
        const float a3 = xs[ty * 4 + 3][k];
        const float4 w0 = *reinterpret_cast<const float4*>(W + (long)k * 256 + cb);
        const float4 w1 = *reinterpret_cast<const float4*>(W + (long)k * 256 + cb + 4);
        const float wreg[8] = {w0.x, w0.y, w0.z, w0.w, w1.x, w1.y, w1.z, w1.w};
        #pragma unroll
        for (int j = 0; j < 8; ++j) {
            acc[0][j] += a0 * wreg[j];
            acc[1][j] += a1 * wreg[j];
            acc[2][j] += a2 * wreg[j];
            acc[3][j] += a3 * wreg[j];
        }
    }
    const int ocb = (tx < 32) ? cb : (256 + cb);
    #pragma unroll
    for (int i = 0; i < 4; ++i)
        #pragma unroll
        for (int j = 0; j < 8; ++j)
            os[ty * 4 + i][ocb + j] = acc[i][j] + bias[cb + j];
    __syncthreads();

    if (tid < 128) {
        const int t = tid >> 3, h = tid & 7;
        const float* xm = &os[t][256 + h * 32];
        const float it = 1.f / temp[h];
        float lg[32];
        float mx = -1e30f;
        #pragma unroll
        for (int g = 0; g < 32; ++g) {
            float a = bsl[g];
            #pragma unroll
            for (int d = 0; d < 32; ++d) a += xm[d] * Wsl[d * 32 + g];
            a *= it;
            lg[g] = a;
            mx = fmaxf(mx, a);
        }
        float ssum = 0.f;
        #pragma unroll
        for (int g = 0; g < 32; ++g) { lg[g] = expf(lg[g] - mx); ssum += lg[g]; }
        const float inv = 1.f / ssum;
        __hip_bfloat16* swp = sw_o + (tok0 + t) * 256 + h * 32;
        #pragma unroll
        for (int g = 0; g < 32; ++g) swp[g] = __float2bfloat16(lg[g] * inv);
    }

    for (int idx = tid; idx < 16 * 256; idx += 256) {
        const int t = idx >> 8, c = idx & 255;
        fxm_o[(tok0 + t) * 256 + c] = __float2bfloat16(os[t][c]);
    }
}

// ---------------------------------------------------------------------------
// Kernel 2: st partials (deterministic two-stage reduction).
// ---------------------------------------------------------------------------
__global__ __launch_bounds__(256) void k2_st_partial(
    const __hip_bfloat16* __restrict__ fxm, const __hip_bfloat16* __restrict__ sw,
    float* __restrict__ pst, float* __restrict__ pn)
{
    __shared__ float fl[8][32];
    __shared__ float sl[8][32];
    const int tid = threadIdx.x;
    const int blk = blockIdx.x;
    const int bh = blk >> 4, chunk = blk & 15;
    const int b = bh >> 3, h = bh & 7;
    const long nbase = (long)b * NTOK + (long)chunk * 2048;
    const int g = tid >> 3, dq = tid & 7, db = dq * 4;
    const int tl = tid >> 5, jj = tid & 31;
    float a0 = 0.f, a1 = 0.f, a2 = 0.f, a3 = 0.f, nacc = 0.f;

    for (int nb = 0; nb < 2048; nb += 8) {
        const long base = (nbase + nb + tl) * 256 + h * 32 + jj;
        fl[tl][jj] = __bfloat162float(fxm[base]);
        sl[tl][jj] = __bfloat162float(sw[base]);
        __syncthreads();
        #pragma unroll
        for (int t = 0; t < 8; ++t) {
            const float s = sl[t][g];
            if (dq == 0) nacc += s;
            a0 += s * fl[t][db + 0];
            a1 += s * fl[t][db + 1];
            a2 += s * fl[t][db + 2];
            a3 += s * fl[t][db + 3];
        }
        __syncthreads();
    }
    float* o = pst + (long)blk * 1024 + g * 32 + db;
    o[0] = a0; o[1] = a1; o[2] = a2; o[3] = a3;
    if (dq == 0) pn[blk * 32 + g] = nacc;
}

// ---------------------------------------------------------------------------
// Kernel 3: reduce partials -> st; slice self-attn + cross-attn -> ost.
// ---------------------------------------------------------------------------
__global__ __launch_bounds__(256) void k3_slice_attn(
    const float* __restrict__ pst, const float* __restrict__ pn,
    const float* __restrict__ ctx,
    const float* __restrict__ Wq, const float* __restrict__ Wk, const float* __restrict__ Wv,
    const float* __restrict__ Wcq, const float* __restrict__ bcq,
    const float* __restrict__ Wck, const float* __restrict__ bck,
    const float* __restrict__ Wcv, const float* __restrict__ bcv,
    const float* __restrict__ mix, float* __restrict__ ost_o)
{
    __shared__ float st[1024], qm[1024], km[1024], vm[1024], cqm[1024];
    __shared__ float ckm[2048], cvm[2048], attn[2048], stok[1024], nb[32];
    const int tid = threadIdx.x;
    const int bh = blockIdx.x;

    if (tid < 32) {
        float s = 0.f;
        for (int c = 0; c < 16; ++c) s += pn[(bh * 16 + c) * 32 + tid];
        nb[tid] = s;
    }
    __syncthreads();
    for (int i = tid; i < 1024; i += 256) {
        float s = 0.f;
        for (int c = 0; c < 16; ++c) s += pst[(long)(bh * 16 + c) * 1024 + i];
        st[i] = s / (nb[i >> 5] + 1e-5f);
    }
    __syncthreads();

    for (int i = tid; i < 1024; i += 256) {
        const int g = i >> 5, d = i & 31;
        float aq = 0.f, ak = 0.f, av = 0.f, ac = bcq[d];
        #pragma unroll
        for (int e = 0; e < 32; ++e) {
            const float s = st[g * 32 + e];
            aq += s * Wq[e * 32 + d];
            ak += s * Wk[e * 32 + d];
            av += s * Wv[e * 32 + d];
            ac += s * Wcq[e * 32 + d];
        }
        qm[i] = aq; km[i] = ak; vm[i] = av; cqm[i] = ac;
    }
    const float* cbp = ctx + (long)bh * (NSC * NDC);
    for (int i = tid; i < 2048; i += 256) {
        const int s_ = i >> 5, d = i & 31;
        float w1 = bck[d], w2 = bcv[d];
        #pragma unroll
        for (int e = 0; e < 32; ++e) {
            const float cval = cbp[s_ * 32 + e];
            w1 += cval * Wck[e * 32 + d];
            w2 += cval * Wcv[e * 32 + d];
        }
        ckm[i] = w1; cvm[i] = w2;
    }
    __syncthreads();

    const float scale = 0.17677669529663687f;
    for (int i = tid; i < 1024; i += 256) {
        const int g = i >> 5, m = i & 31;
        float a = 0.f;
        #pragma unroll
        for (int d = 0; d < 32; ++d) a += qm[g * 32 + d] * km[m * 32 + d];
        attn[i] = a * scale;
    }
    __syncthreads();
    if (tid < 32) {
        float mx = -1e30f;
        for (int m = 0; m < 32; ++m) mx = fmaxf(mx, attn[tid * 32 + m]);
        float s = 0.f;
        for (int m = 0; m < 32; ++m) { const float e = expf(attn[tid * 32 + m] - mx); attn[tid * 32 + m] = e; s += e; }
        const float inv = 1.f / s;
        for (int m = 0; m < 32; ++m) attn[tid * 32 + m] *= inv;
    }
    __syncthreads();
    for (int i = tid; i < 1024; i += 256) {
        const int g = i >> 5, d = i & 31;
        float a = 0.f;
        #pragma unroll
        for (int m = 0; m < 32; ++m) a += attn[g * 32 + m] * vm[m * 32 + d];
        stok[i] = a;
    }
    __syncthreads();
    for (int i = tid; i < 2048; i += 256) {
        const int g = i >> 6, s_ = i & 63;
        float a = 0.f;
        #pragma unroll
        for (int d = 0; d < 32; ++d) a += cqm[g * 32 + d] * ckm[s_ * 32 + d];
        attn[i] = a * scale;
    }
    __syncthreads();
    if (tid < 32) {
        float mx = -1e30f;
        for (int m = 0; m < 64; ++m) mx = fmaxf(mx, attn[tid * 64 + m]);
        float s = 0.f;
        for (int m = 0; m < 64; ++m) { const float e = expf(attn[tid * 64 + m] - mx); attn[tid * 64 + m] = e; s += e; }
        const float inv = 1.f / s;
        for (int m = 0; m < 64; ++m) attn[tid * 64 + m] *= inv;
    }
    __syncthreads();
    const float mw = 1.f / (1.f + expf(-mix[0]));
    for (int i = tid; i < 1024; i += 256) {
        const int g = i >> 5, d = i & 31;
        float a = 0.f;
        #pragma unroll
        for (int s_ = 0; s_ < 64; ++s_) a += attn[g * 64 + s_] * cvm[s_ * 32 + d];
        ost_o[(long)bh * 1024 + i] = mw * stok[i] + (1.f - mw) * a;
    }
}

// ---------------------------------------------------------------------------
// Kernel 4: de-slice + Wout GEMM + residual -> d_out.
// ---------------------------------------------------------------------------
__global__ __launch_bounds__(256) void k4_deslice_out(
    const __hip_bfloat16* __restrict__ sw, const float* __restrict__ ost,
    const float* __restrict__ Wout, const float* __restrict__ bout,
    const float* __restrict__ fx, float* __restrict__ out)
{
    __shared__ float ol[8192];
    __shared__ float al[16][256];
    __shared__ __hip_bfloat16 swl[16 * 256];
    const int tid = threadIdx.x;
    const long tok0 = (long)blockIdx.x * 16;
    const int b = (int)(tok0 >> 15);

    for (int i = tid; i < 8192; i += 256) ol[i] = ost[b * 8192 + i];
    for (int i = tid; i < 4096; i += 256) swl[i] = sw[tok0 * 256 + i];
    __syncthreads();

    for (int i = tid; i < 4096; i += 256) {
        const int t = i >> 8, c = i & 255;
        const int h = c >> 5, d = c & 31;
        const __hip_bfloat16* swr = &swl[t * 256 + h * 32];
        const float* op = &ol[h * 1024 + d];
        float a = 0.f;
        #pragma unroll
        for (int g = 0; g < 32; ++g) a += __bfloat162float(swr[g]) * op[g * 32];
        al[t][c] = a;
    }
    __syncthreads();

    const int tx = tid & 63, ty = tid >> 6;
    const int cb = tx * 4;
    float acc[4][4];
    #pragma unroll
    for (int i = 0; i < 4; ++i)
        #pragma unroll
        for (int j = 0; j < 4; ++j) acc[i][j] = 0.f;

    #pragma unroll 4
    for (int k = 0; k < 256; ++k) {
        const float4 w = *reinterpret_cast<const float4*>(Wout + (long)k * 256 + cb);
        #pragma unroll
        for (int i = 0; i < 4; ++i) {
            const float a = al[ty * 4 + i][k];
            acc[i][0] += a * w.x; acc[i][1] += a * w.y;
            acc[i][2] += a * w.z; acc[i][3] += a * w.w;
        }
    }
    const float4 bo = *reinterpret_cast<const float4*>(bout + cb);
    #pragma unroll
    for (int i = 0; i < 4; ++i) {
        const long r = (tok0 + ty * 4 + i) * 256 + cb;
        const float4 f = *reinterpret_cast<const float4*>(fx + r);
        float4 o;
        o.x = acc[i][0] + bo.x + f.x;
        o.y = acc[i][1] + bo.y + f.y;
        o.z = acc[i][2] + bo.z + f.z;
        o.w = acc[i][3] + bo.w + f.w;
        *reinterpret_cast<float4*>(out + r) = o;
    }
}

// ---------------------------------------------------------------------------
// Weight transpose+convert: in f32 [K][N] -> out bf16 [N][K].
// ---------------------------------------------------------------------------
__global__ __launch_bounds__(256) void kconv_transpose(
    const float* __restrict__ in, __hip_bfloat16* __restrict__ out,
    int K, int N)
{
    __shared__ float t[32][33];
    const int nb = N >> 5;
    const int bk = blockIdx.x / nb;
    const int bn = blockIdx.x % nb;
    const int c = threadIdx.x & 31, r0 = threadIdx.x >> 5;
    #pragma unroll
    for (int i = 0; i < 4; ++i) {
        const int r = r0 + i * 8;
        t[r][c] = in[(long)(bk * 32 + r) * N + bn * 32 + c];
    }
    __syncthreads();
    #pragma unroll
    for (int i = 0; i < 4; ++i) {
        const int r = r0 + i * 8;
        out[(long)(bn * 32 + r) * K + bk * 32 + c] = __float2bfloat16(t[c][r]);
    }
}

// ---------------------------------------------------------------------------
// Kernel 5 (MFMA): fused MLP. 64 tokens/block, 256 threads (4 waves).
// A (LN2 out, bf16) and A2 (gelu hidden chunk, bf16) live in XOR-swizzled LDS.
// W1T [1024][256] bf16, W2T [256][1024] bf16 read as B-fragments from L2.
// ---------------------------------------------------------------------------
__global__ __launch_bounds__(256) void k5_mlp_mfma(
    float* __restrict__ io,
    const float* __restrict__ g2, const float* __restrict__ b2,
    const __hip_bfloat16* __restrict__ w1t, const float* __restrict__ bm1,
    const __hip_bfloat16* __restrict__ w2t, const float* __restrict__ bm2)
{
    __shared__ __align__(16) char lds[65536];   // [0,32K): A   [32K,64K): A2
    const int tid = threadIdx.x;
    const int lane = tid & 63, wid = tid >> 6;
    const long tok0 = (long)blockIdx.x * 64;
    const int col = lane & 15, kq = lane >> 4;   // MFMA fragment coords
    const int n0 = wid * 64;                     // wave's n-slice

    // ---- LN2 -> A (bf16, swizzled). Each wave: 16 tokens. ----
    {
        const float4 gv = *reinterpret_cast<const float4*>(g2 + lane * 4);
        const float4 bv = *reinterpret_cast<const float4*>(b2 + lane * 4);
        for (int tt = 0; tt < 16; ++tt) {
            const int r = wid * 16 + tt;
            const float4 v = *reinterpret_cast<const float4*>(io + (tok0 + r) * 256 + lane * 4);
            float s = v.x + v.y + v.z + v.w;
            float s2 = v.x * v.x + v.y * v.y + v.z * v.z + v.w * v.w;
            #pragma unroll
            for (int off = 32; off; off >>= 1) {
                s  += __shfl_xor(s,  off);
                s2 += __shfl_xor(s2, off);
            }
            const float mean = s * (1.f / 256.f);
            const float rs = rsqrtf(s2 * (1.f / 256.f) - mean * mean + 1e-5f);
            short4v o;
            o[0] = f2bf((v.x - mean) * rs * gv.x + bv.x);
            o[1] = f2bf((v.y - mean) * rs * gv.y + bv.y);
            o[2] = f2bf((v.z - mean) * rs * gv.z + bv.z);
            o[3] = f2bf((v.w - mean) * rs * gv.w + bv.w);
            const int addr = r * 512 + ((lane * 8) ^ ((r & 7) << 4));
            *reinterpret_cast<short4v*>(lds + addr) = o;
        }
    }
    __syncthreads();

    f32x4 accO[4][4];
    #pragma unroll
    for (int mt = 0; mt < 4; ++mt)
        #pragma unroll
        for (int nt = 0; nt < 4; ++nt) accO[mt][nt] = (f32x4){0.f, 0.f, 0.f, 0.f};

    for (int ch = 0; ch < 4; ++ch) {
        // ---- GEMM1: P(64 x wave's 64) = A @ W1[:, ch*256 + n0 .. +64] ----
        f32x4 accP[4][4];
        #pragma unroll
        for (int mt = 0; mt < 4; ++mt)
            #pragma unroll
            for (int nt = 0; nt < 4; ++nt) accP[mt][nt] = (f32x4){0.f, 0.f, 0.f, 0.f};

        #pragma unroll 2
        for (int ks = 0; ks < 8; ++ks) {
            short8v a[4], b[4];
            #pragma unroll
            for (int mt = 0; mt < 4; ++mt) {
                const int row = mt * 16 + col;
                const int byte = row * 512 + ((ks * 64 + kq * 16) ^ ((row & 7) << 4));
                a[mt] = *reinterpret_cast<const short8v*>(lds + byte);
            }
            #pragma unroll
            for (int nt = 0; nt < 4; ++nt) {
                const long ng = (long)(ch * 256 + n0 + nt * 16 + col);
                b[nt] = *reinterpret_cast<const short8v*>(w1t + ng * 256 + ks * 32 + kq * 8);
            }
            #pragma unroll
            for (int mt = 0; mt < 4; ++mt)
                #pragma unroll
                for (int nt = 0; nt < 4; ++nt)
                    accP[mt][nt] = __builtin_amdgcn_mfma_f32_16x16x32_bf16(
                        a[mt], b[nt], accP[mt][nt], 0, 0, 0);
        }

        // ---- bias + exact GELU -> A2 (bf16, swizzled) ----
        __syncthreads();   // all waves done reading A2 of previous chunk
        #pragma unroll
        for (int nt = 0; nt < 4; ++nt) {
            const float b1v = bm1[ch * 256 + n0 + nt * 16 + col];
            const int k2i = n0 + nt * 16 + col;    // chunk-local hidden index
            #pragma unroll
            for (int mt = 0; mt < 4; ++mt) {
                #pragma unroll
                for (int r = 0; r < 4; ++r) {
                    float m = accP[mt][nt][r] + b1v;
                    m = 0.5f * m * (1.f + erff(m * 0.70710678118f));
                    const int row = mt * 16 + kq * 4 + r;
                    const int byte = 32768 + row * 512 + ((k2i * 2) ^ ((row & 7) << 4));
                    *reinterpret_cast<short*>(lds + byte) = f2bf(m);
                }
            }
        }
        __syncthreads();

        // ---- GEMM2: accO += A2 @ W2[ch*256.., :] ----
        #pragma unroll 2
        for (int ks = 0; ks < 8; ++ks) {
            short8v a[4], b[4];
            #pragma unroll
            for (int mt = 0; mt < 4; ++mt) {
                const int row = mt * 16 + col;
                const int byte = 32768 + row * 512 + ((ks * 64 + kq * 16) ^ ((row & 7) << 4));
                a[mt] = *reinterpret_cast<const short8v*>(lds + byte);
            }
            #pragma unroll
            for (int nt = 0; nt < 4; ++nt) {
                const long ng = (long)(n0 + nt * 16 + col);
                b[nt] = *reinterpret_cast<const short8v*>(w2t + ng * 1024 + ch * 256 + ks * 32 + kq * 8);
            }
            #pragma unroll
            for (int mt = 0; mt < 4; ++mt)
                #pragma unroll
                for (int nt = 0; nt < 4; ++nt)
                    accO[mt][nt] = __builtin_amdgcn_mfma_f32_16x16x32_bf16(
                        a[mt], b[nt], accO[mt][nt], 0, 0, 0);
        }
    }

    // ---- epilogue: bias + residual + store ----
    #pragma unroll
    for (int nt = 0; nt < 4; ++nt) {
        const float b2v = bm2[n0 + nt * 16 + col];
        #pragma unroll
        for (int mt = 0; mt < 4; ++mt) {
            #pragma unroll
            for (int r = 0; r < 4; ++r) {
                const int row = mt * 16 + kq * 4 + r;
                const long idx = (tok0 + row) * 256 + n0 + nt * 16 + col;
                io[idx] = io[idx] + accO[mt][nt][r] + b2v;
            }
        }
    }
}

// ---------------------------------------------------------------------------
extern "C" void kernel_launch(void* const* d_in, const int* in_sizes, int n_in,
                              void* d_out, int out_size, void* d_ws, size_t ws_size,
                              hipStream_t stream)
{
    const float* fx   = (const float*)d_in[0];
    const float* ctx  = (const float*)d_in[1];
    const float* g1   = (const float*)d_in[2];
    const float* b1   = (const float*)d_in[3];
    const float* Wfx  = (const float*)d_in[4];
    const float* bfx  = (const float*)d_in[5];
    const float* Wx   = (const float*)d_in[6];
    const float* bx   = (const float*)d_in[7];
    const float* Wsl  = (const float*)d_in[8];
    const float* bsl  = (const float*)d_in[9];
    const float* temp = (const float*)d_in[10];
    const float* Wq   = (const float*)d_in[11];
    const float* Wk   = (const float*)d_in[12];
    const float* Wv   = (const float*)d_in[13];
    const float* Wcq  = (const float*)d_in[14];
    const float* bcq  = (const float*)d_in[15];
    const float* Wck  = (const float*)d_in[16];
    const float* bck  = (const float*)d_in[17];
    const float* Wcv  = (const float*)d_in[18];
    const float* bcv  = (const float*)d_in[19];
    const float* mix  = (const float*)d_in[20];
    const float* Wout = (const float*)d_in[21];
    const float* bout = (const float*)d_in[22];
    const float* g2   = (const float*)d_in[23];
    const float* b2   = (const float*)d_in[24];
    const float* Wm1  = (const float*)d_in[25];
    const float* bm1  = (const float*)d_in[26];
    const float* Wm2  = (const float*)d_in[27];
    const float* bm2  = (const float*)d_in[28];
    float* out = (float*)d_out;

    char* ws = (char*)d_ws;
    __hip_bfloat16* fxm = (__hip_bfloat16*)ws;                          // 32MB
    __hip_bfloat16* sw  = (__hip_bfloat16*)(ws + (size_t)33554432);     // 32MB
    float* pst = (float*)(ws + (size_t)67108864);                       // 1MB
    float* pn  = (float*)(ws + (size_t)67108864 + 1048576);             // 32KB
    float* ost = (float*)(ws + (size_t)67108864 + 1048576 + 32768);     // 64KB
    // After k3, pst's 1MB is dead -> reuse for bf16 transposed MLP weights.
    __hip_bfloat16* w1t = (__hip_bfloat16*)(ws + (size_t)67108864);              // 512KB [1024][256]
    __hip_bfloat16* w2t = (__hip_bfloat16*)(ws + (size_t)67108864 + 524288);     // 512KB [256][1024]

    k1_ln_gemm_slice<<<4096, 256, 0, stream>>>(fx, g1, b1, Wfx, bfx, Wx, bx,
                                               Wsl, bsl, temp, fxm, sw);
    k2_st_partial<<<256, 256, 0, stream>>>(fxm, sw, pst, pn);
    k3_slice_attn<<<16, 256, 0, stream>>>(pst, pn, ctx, Wq, Wk, Wv,
                                          Wcq, bcq, Wck, bck, Wcv, bcv, mix, ost);
    kconv_transpose<<<256, 256, 0, stream>>>(Wm1, w1t, 256, 1024);
    kconv_transpose<<<256, 256, 0, stream>>>(Wm2, w2t, 1024, 256);
    k4_deslice_out<<<4096, 256, 0, stream>>>(sw, ost, Wout, bout, fx, out);
    k5_mlp_mfma<<<1024, 256, 0, stream>>>(out, g2, b2, w1t, bm1, w2t, bm2);
}

// Round 3
// 505.887 us; speedup vs baseline: 6.6241x; 1.6764x over previous
//
#include <hip/hip_runtime.h>
#include <hip/hip_bf16.h>

#define BATCH 2
#define NTOK  32768
#define CH    256
#define NH    8
#define HDIM  32
#define NG    32
#define NSC   64
#define NDC   32

typedef __attribute__((ext_vector_type(8))) short short8v;
typedef __attribute__((ext_vector_type(4))) short short4v;
typedef __attribute__((ext_vector_type(4))) float f32x4;

static __device__ __forceinline__ short f2bf(float f) {
    __hip_bfloat16 h = __float2bfloat16(f);
    return __builtin_bit_cast(short, h);
}
static __device__ __forceinline__ float bf2f(short s) {
    return __bfloat162float(__builtin_bit_cast(__hip_bfloat16, s));
}

// ---------------------------------------------------------------------------
// Weight transpose+convert: in f32 [K][N] -> out bf16 [N][K].
// ---------------------------------------------------------------------------
__global__ __launch_bounds__(256) void kconv_transpose(
    const float* __restrict__ in, __hip_bfloat16* __restrict__ out,
    int K, int N)
{
    __shared__ float t[32][33];
    const int nb = N >> 5;
    const int bk = blockIdx.x / nb;
    const int bn = blockIdx.x % nb;
    const int c = threadIdx.x & 31, r0 = threadIdx.x >> 5;
    #pragma unroll
    for (int i = 0; i < 4; ++i) {
        const int r = r0 + i * 8;
        t[r][c] = in[(long)(bk * 32 + r) * N + bn * 32 + c];
    }
    __syncthreads();
    #pragma unroll
    for (int i = 0; i < 4; ++i) {
        const int r = r0 + i * 8;
        out[(long)(bn * 32 + r) * K + bk * 32 + c] = __float2bfloat16(t[c][r]);
    }
}

// ---------------------------------------------------------------------------
// Kernel 1 (MFMA): LN1 + dual GEMM (x@[Wfx|Wx]) + slice softmax.
// 64 tokens/block, 4 waves. A bf16 swizzled in LDS [0,32K); after GEMM the
// 64KB os buffer (bf16 [64][512]) overlays the whole LDS.
// ---------------------------------------------------------------------------
__global__ __launch_bounds__(256, 2) void k1_mfma(
    const float* __restrict__ fx,
    const float* __restrict__ g1, const float* __restrict__ b1,
    const __hip_bfloat16* __restrict__ wcat,   // [512][256] = [Wfx^T ; Wx^T]
    const float* __restrict__ bfx, const float* __restrict__ bx,
    const float* __restrict__ Wsl, const float* __restrict__ bsl,
    const float* __restrict__ temp,
    __hip_bfloat16* __restrict__ fxm_o, __hip_bfloat16* __restrict__ sw_o)
{
    __shared__ __align__(16) char lds[65536];
    const int tid = threadIdx.x;
    const int lane = tid & 63, wid = tid >> 6;
    const long tok0 = (long)blockIdx.x * 64;
    const int col = lane & 15, kq = lane >> 4;

    // ---- LN1 -> A (bf16, swizzled, row stride 512B) ----
    {
        const float4 gv = *reinterpret_cast<const float4*>(g1 + lane * 4);
        const float4 bv = *reinterpret_cast<const float4*>(b1 + lane * 4);
        for (int tt = 0; tt < 16; ++tt) {
            const int r = wid * 16 + tt;
            const float4 v = *reinterpret_cast<const float4*>(fx + (tok0 + r) * 256 + lane * 4);
            float s = v.x + v.y + v.z + v.w;
            float s2 = v.x * v.x + v.y * v.y + v.z * v.z + v.w * v.w;
            #pragma unroll
            for (int off = 32; off; off >>= 1) {
                s  += __shfl_xor(s,  off);
                s2 += __shfl_xor(s2, off);
            }
            const float mean = s * (1.f / 256.f);
            const float rs = rsqrtf(s2 * (1.f / 256.f) - mean * mean + 1e-5f);
            short4v o;
            o[0] = f2bf((v.x - mean) * rs * gv.x + bv.x);
            o[1] = f2bf((v.y - mean) * rs * gv.y + bv.y);
            o[2] = f2bf((v.z - mean) * rs * gv.z + bv.z);
            o[3] = f2bf((v.w - mean) * rs * gv.w + bv.w);
            const int addr = r * 512 + ((lane * 8) ^ ((r & 7) << 4));
            *reinterpret_cast<short4v*>(lds + addr) = o;
        }
    }
    __syncthreads();

    // ---- GEMM: C(64 x 512) = A @ wcat^T ; wave owns n-slice of 128 ----
    f32x4 acc[4][8];
    #pragma unroll
    for (int mt = 0; mt < 4; ++mt)
        #pragma unroll
        for (int nt = 0; nt < 8; ++nt) acc[mt][nt] = (f32x4){0.f, 0.f, 0.f, 0.f};

    for (int ks = 0; ks < 8; ++ks) {
        short8v a[4];
        #pragma unroll
        for (int mt = 0; mt < 4; ++mt) {
            const int row = mt * 16 + col;
            const int byte = row * 512 + ((ks * 64 + kq * 16) ^ ((row & 7) << 4));
            a[mt] = *reinterpret_cast<const short8v*>(lds + byte);
        }
        #pragma unroll
        for (int nt = 0; nt < 8; ++nt) {
            const long ng = (long)(wid * 128 + nt * 16 + col);
            const short8v b = *reinterpret_cast<const short8v*>(
                reinterpret_cast<const short*>(wcat) + ng * 256 + ks * 32 + kq * 8);
            #pragma unroll
            for (int mt = 0; mt < 4; ++mt)
                acc[mt][nt] = __builtin_amdgcn_mfma_f32_16x16x32_bf16(
                    a[mt], b, acc[mt][nt], 0, 0, 0);
        }
    }
    __syncthreads();   // A dead; os overlays [0,64K)

    // ---- write os bf16 [64][512] (row stride 1024B, swizzled) ----
    #pragma unroll
    for (int nt = 0; nt < 8; ++nt) {
        const int c = wid * 128 + nt * 16 + col;
        const float bb = (c < 256) ? bfx[c] : bx[c - 256];
        #pragma unroll
        for (int mt = 0; mt < 4; ++mt) {
            #pragma unroll
            for (int r = 0; r < 4; ++r) {
                const int row = mt * 16 + kq * 4 + r;
                const int byte = row * 1024 + ((c * 2) ^ ((row & 7) << 4));
                *reinterpret_cast<short*>(lds + byte) = f2bf(acc[mt][nt][r] + bb);
            }
        }
    }
    __syncthreads();

    // ---- coalesced fxm store from LDS ----
    #pragma unroll
    for (int it = 0; it < 8; ++it) {
        const int idx = it * 256 + tid;          // 2048 chunks of 16B
        const int row = idx >> 5, ch = idx & 31;
        const short8v val = *reinterpret_cast<const short8v*>(
            lds + row * 1024 + ((ch * 16) ^ ((row & 7) << 4)));
        *reinterpret_cast<short8v*>(
            reinterpret_cast<short*>(fxm_o) + (tok0 + row) * 256 + ch * 8) = val;
    }

    // ---- slice softmax: 512 (token,head) pairs, 2 per thread ----
    #pragma unroll
    for (int pp = 0; pp < 2; ++pp) {
        const int p = pp * 256 + tid;
        const int t = p >> 3, h = p & 7;
        float xm[32];
        #pragma unroll
        for (int d = 0; d < 32; ++d) {
            const int byte = t * 1024 + (((256 + h * 32 + d) * 2) ^ ((t & 7) << 4));
            xm[d] = bf2f(*reinterpret_cast<const short*>(lds + byte));
        }
        float lg[32];
        #pragma unroll
        for (int g = 0; g < 32; ++g) lg[g] = bsl[g];
        for (int d = 0; d < 32; ++d) {
            const float xd = xm[d];
            #pragma unroll
            for (int g4 = 0; g4 < 8; ++g4) {
                const float4 w = *reinterpret_cast<const float4*>(Wsl + d * 32 + g4 * 4);
                lg[g4 * 4 + 0] += xd * w.x;
                lg[g4 * 4 + 1] += xd * w.y;
                lg[g4 * 4 + 2] += xd * w.z;
                lg[g4 * 4 + 3] += xd * w.w;
            }
        }
        const float it_ = 1.f / temp[h];
        float mx = -1e30f;
        #pragma unroll
        for (int g = 0; g < 32; ++g) { lg[g] *= it_; mx = fmaxf(mx, lg[g]); }
        float ssum = 0.f;
        #pragma unroll
        for (int g = 0; g < 32; ++g) { lg[g] = expf(lg[g] - mx); ssum += lg[g]; }
        const float inv = 1.f / ssum;
        __hip_bfloat16* swp = sw_o + (tok0 + t) * 256 + h * 32;
        #pragma unroll
        for (int g = 0; g < 32; ++g) swp[g] = __float2bfloat16(lg[g] * inv);
    }
}

// ---------------------------------------------------------------------------
// Kernel 2: st partials. 512 blocks (32 chunks per (b,h)), 1024 rows each,
// 32-row bf16 LDS tiles. Deterministic.
// ---------------------------------------------------------------------------
__global__ __launch_bounds__(256) void k2_st_partial(
    const __hip_bfloat16* __restrict__ fxm, const __hip_bfloat16* __restrict__ sw,
    float* __restrict__ pst, float* __restrict__ pn)
{
    __shared__ float fl[32][32];
    __shared__ float sl[32][32];
    const int tid = threadIdx.x;
    const int blk = blockIdx.x;
    const int bh = blk >> 5, chunk = blk & 31;
    const int b = bh >> 3, h = bh & 7;
    const long nbase = (long)b * NTOK + (long)chunk * 1024;
    const int g = tid >> 3, dq = tid & 7, db = dq * 4;
    const int lr = tid >> 3, lc4 = (tid & 7) * 4;
    float a0 = 0.f, a1 = 0.f, a2 = 0.f, a3 = 0.f, nacc = 0.f;

    for (int nb = 0; nb < 1024; nb += 32) {
        const long base = (nbase + nb + lr) * 256 + h * 32 + lc4;
        const short4v fv = *reinterpret_cast<const short4v*>(
            reinterpret_cast<const short*>(fxm) + base);
        const short4v sv = *reinterpret_cast<const short4v*>(
            reinterpret_cast<const short*>(sw) + base);
        float4 ff, sf;
        ff.x = bf2f(fv[0]); ff.y = bf2f(fv[1]); ff.z = bf2f(fv[2]); ff.w = bf2f(fv[3]);
        sf.x = bf2f(sv[0]); sf.y = bf2f(sv[1]); sf.z = bf2f(sv[2]); sf.w = bf2f(sv[3]);
        __syncthreads();
        *reinterpret_cast<float4*>(&fl[lr][lc4]) = ff;
        *reinterpret_cast<float4*>(&sl[lr][lc4]) = sf;
        __syncthreads();
        #pragma unroll
        for (int t = 0; t < 32; ++t) {
            const float s = sl[t][g];
            if (dq == 0) nacc += s;
            a0 += s * fl[t][db + 0];
            a1 += s * fl[t][db + 1];
            a2 += s * fl[t][db + 2];
            a3 += s * fl[t][db + 3];
        }
    }
    float* o = pst + (long)blk * 1024 + g * 32 + db;
    o[0] = a0; o[1] = a1; o[2] = a2; o[3] = a3;
    if (dq == 0) pn[blk * 32 + g] = nacc;
}

// ---------------------------------------------------------------------------
// Kernel 3: reduce partials -> st; slice self-attn + cross-attn -> ostT (bf16).
// ---------------------------------------------------------------------------
__global__ __launch_bounds__(256) void k3_slice_attn(
    const float* __restrict__ pst, const float* __restrict__ pn,
    const float* __restrict__ ctx,
    const float* __restrict__ Wq, const float* __restrict__ Wk, const float* __restrict__ Wv,
    const float* __restrict__ Wcq, const float* __restrict__ bcq,
    const float* __restrict__ Wck, const float* __restrict__ bck,
    const float* __restrict__ Wcv, const float* __restrict__ bcv,
    const float* __restrict__ mix, __hip_bfloat16* __restrict__ ostT_o)
{
    __shared__ float st[1024], qm[1024], km[1024], vm[1024], cqm[1024];
    __shared__ float ckm[2048], cvm[2048], attn[2048], stok[1024], nb[32];
    const int tid = threadIdx.x;
    const int bh = blockIdx.x;

    if (tid < 32) {
        float s = 0.f;
        for (int c = 0; c < 32; ++c) s += pn[(bh * 32 + c) * 32 + tid];
        nb[tid] = s;
    }
    __syncthreads();
    for (int i = tid; i < 1024; i += 256) {
        float s = 0.f;
        for (int c = 0; c < 32; ++c) s += pst[(long)(bh * 32 + c) * 1024 + i];
        st[i] = s / (nb[i >> 5] + 1e-5f);
    }
    __syncthreads();

    for (int i = tid; i < 1024; i += 256) {
        const int g = i >> 5, d = i & 31;
        float aq = 0.f, ak = 0.f, av = 0.f, ac = bcq[d];
        #pragma unroll
        for (int e = 0; e < 32; ++e) {
            const float s = st[g * 32 + e];
            aq += s * Wq[e * 32 + d];
            ak += s * Wk[e * 32 + d];
            av += s * Wv[e * 32 + d];
            ac += s * Wcq[e * 32 + d];
        }
        qm[i] = aq; km[i] = ak; vm[i] = av; cqm[i] = ac;
    }
    const float* cbp = ctx + (long)bh * (NSC * NDC);
    for (int i = tid; i < 2048; i += 256) {
        const int s_ = i >> 5, d = i & 31;
        float w1 = bck[d], w2 = bcv[d];
        #pragma unroll
        for (int e = 0; e < 32; ++e) {
            const float cval = cbp[s_ * 32 + e];
            w1 += cval * Wck[e * 32 + d];
            w2 += cval * Wcv[e * 32 + d];
        }
        ckm[i] = w1; cvm[i] = w2;
    }
    __syncthreads();

    const float scale = 0.17677669529663687f;
    for (int i = tid; i < 1024; i += 256) {
        const int g = i >> 5, m = i & 31;
        float a = 0.f;
        #pragma unroll
        for (int d = 0; d < 32; ++d) a += qm[g * 32 + d] * km[m * 32 + d];
        attn[i] = a * scale;
    }
    __syncthreads();
    if (tid < 32) {
        float mx = -1e30f;
        for (int m = 0; m < 32; ++m) mx = fmaxf(mx, attn[tid * 32 + m]);
        float s = 0.f;
        for (int m = 0; m < 32; ++m) { const float e = expf(attn[tid * 32 + m] - mx); attn[tid * 32 + m] = e; s += e; }
        const float inv = 1.f / s;
        for (int m = 0; m < 32; ++m) attn[tid * 32 + m] *= inv;
    }
    __syncthreads();
    for (int i = tid; i < 1024; i += 256) {
        const int g = i >> 5, d = i & 31;
        float a = 0.f;
        #pragma unroll
        for (int m = 0; m < 32; ++m) a += attn[g * 32 + m] * vm[m * 32 + d];
        stok[i] = a;
    }
    __syncthreads();
    for (int i = tid; i < 2048; i += 256) {
        const int g = i >> 6, s_ = i & 63;
        float a = 0.f;
        #pragma unroll
        for (int d = 0; d < 32; ++d) a += cqm[g * 32 + d] * ckm[s_ * 32 + d];
        attn[i] = a * scale;
    }
    __syncthreads();
    if (tid < 32) {
        float mx = -1e30f;
        for (int m = 0; m < 64; ++m) mx = fmaxf(mx, attn[tid * 64 + m]);
        float s = 0.f;
        for (int m = 0; m < 64; ++m) { const float e = expf(attn[tid * 64 + m] - mx); attn[tid * 64 + m] = e; s += e; }
        const float inv = 1.f / s;
        for (int m = 0; m < 64; ++m) attn[tid * 64 + m] *= inv;
    }
    __syncthreads();
    const float mw = 1.f / (1.f + expf(-mix[0]));
    for (int i = tid; i < 1024; i += 256) {
        const int g = i >> 5, d = i & 31;
        float a = 0.f;
        #pragma unroll
        for (int s_ = 0; s_ < 64; ++s_) a += attn[g * 64 + s_] * cvm[s_ * 32 + d];
        const float val = mw * stok[i] + (1.f - mw) * a;
        ostT_o[(long)bh * 1024 + d * 32 + g] = __float2bfloat16(val);   // [bh][d][g]
    }
}

// ---------------------------------------------------------------------------
// Kernel 4 (MFMA): de-slice (MFMA, K=32 per head) + Wout GEMM + residual.
// 64 tokens/block, 4 waves. LDS: [0,32K) swl bf16 swizzled; [32K,64K) al.
// ---------------------------------------------------------------------------
__global__ __launch_bounds__(256, 2) void k4_mfma(
    const __hip_bfloat16* __restrict__ sw, const __hip_bfloat16* __restrict__ ostT,
    const __hip_bfloat16* __restrict__ woutt, const float* __restrict__ bout,
    const float* __restrict__ fx, float* __restrict__ out)
{
    __shared__ __align__(16) char lds[65536];
    const int tid = threadIdx.x;
    const int lane = tid & 63, wid = tid >> 6;
    const long tok0 = (long)blockIdx.x * 64;
    const int b = (int)(tok0 >> 15);
    const int col = lane & 15, kq = lane >> 4;

    // ---- stage sw -> swl (bf16 [64][256], swizzled, row stride 512B) ----
    #pragma unroll
    for (int it = 0; it < 8; ++it) {
        const int idx = it * 256 + tid;          // 2048 chunks of 16B
        const int row = idx >> 5, ch = idx & 31;
        const short8v val = *reinterpret_cast<const short8v*>(
            reinterpret_cast<const short*>(sw) + (tok0 + row) * 256 + ch * 8);
        *reinterpret_cast<short8v*>(lds + row * 512 + ((ch * 16) ^ ((row & 7) << 4))) = val;
    }
    __syncthreads();

    // ---- de-slice via MFMA: wave handles heads wid*2, wid*2+1 ----
    f32x4 accal[2][4][2];
    #pragma unroll
    for (int hh = 0; hh < 2; ++hh) {
        const int h = wid * 2 + hh;
        short8v a[4];
        #pragma unroll
        for (int mt = 0; mt < 4; ++mt) {
            const int row = mt * 16 + col;
            const int byte = row * 512 + (((h * 32 + kq * 8) * 2) ^ ((row & 7) << 4));
            a[mt] = *reinterpret_cast<const short8v*>(lds + byte);
        }
        #pragma unroll
        for (int nt = 0; nt < 2; ++nt) {
            const int d = nt * 16 + col;
            const short8v bfr = *reinterpret_cast<const short8v*>(
                reinterpret_cast<const short*>(ostT) + ((b * 8 + h) * 32 + d) * 32 + kq * 8);
            #pragma unroll
            for (int mt = 0; mt < 4; ++mt) {
                accal[hh][mt][nt] = (f32x4){0.f, 0.f, 0.f, 0.f};
                accal[hh][mt][nt] = __builtin_amdgcn_mfma_f32_16x16x32_bf16(
                    a[mt], bfr, accal[hh][mt][nt], 0, 0, 0);
            }
        }
    }
    // ---- write al (bf16 [64][256], swizzled) into [32K,64K) ----
    #pragma unroll
    for (int hh = 0; hh < 2; ++hh) {
        const int h = wid * 2 + hh;
        #pragma unroll
        for (int nt = 0; nt < 2; ++nt) {
            const int cc = h * 32 + nt * 16 + col;
            #pragma unroll
            for (int mt = 0; mt < 4; ++mt) {
                #pragma unroll
                for (int r = 0; r < 4; ++r) {
                    const int row = mt * 16 + kq * 4 + r;
                    const int byte = 32768 + row * 512 + ((cc * 2) ^ ((row & 7) << 4));
                    *reinterpret_cast<short*>(lds + byte) = f2bf(accal[hh][mt][nt][r]);
                }
            }
        }
    }
    __syncthreads();

    // ---- main GEMM: out(64x256) = al @ Wout ; wave n-slice 64 ----
    f32x4 acc[4][4];
    #pragma unroll
    for (int mt = 0; mt < 4; ++mt)
        #pragma unroll
        for (int nt = 0; nt < 4; ++nt) acc[mt][nt] = (f32x4){0.f, 0.f, 0.f, 0.f};

    for (int ks = 0; ks < 8; ++ks) {
        short8v a[4];
        #pragma unroll
        for (int mt = 0; mt < 4; ++mt) {
            const int row = mt * 16 + col;
            const int byte = 32768 + row * 512 + ((ks * 64 + kq * 16) ^ ((row & 7) << 4));
            a[mt] = *reinterpret_cast<const short8v*>(lds + byte);
        }
        #pragma unroll
        for (int nt = 0; nt < 4; ++nt) {
            const long ng = (long)(wid * 64 + nt * 16 + col);
            const short8v bfr = *reinterpret_cast<const short8v*>(
                reinterpret_cast<const short*>(woutt) + ng * 256 + ks * 32 + kq * 8);
            #pragma unroll
            for (int mt = 0; mt < 4; ++mt)
                acc[mt][nt] = __builtin_amdgcn_mfma_f32_16x16x32_bf16(
                    a[mt], bfr, acc[mt][nt], 0, 0, 0);
        }
    }

    // ---- epilogue: + bout + fx residual -> out ----
    #pragma unroll
    for (int nt = 0; nt < 4; ++nt) {
        const int c = wid * 64 + nt * 16 + col;
        const float bb = bout[c];
        #pragma unroll
        for (int mt = 0; mt < 4; ++mt) {
            #pragma unroll
            for (int r = 0; r < 4; ++r) {
                const int row = mt * 16 + kq * 4 + r;
                const long idx = (tok0 + row) * 256 + c;
                out[idx] = acc[mt][nt][r] + bb + fx[idx];
            }
        }
    }
}

// ---------------------------------------------------------------------------
// Kernel 5 (MFMA): fused MLP (unchanged from round 2).
// ---------------------------------------------------------------------------
__global__ __launch_bounds__(256) void k5_mlp_mfma(
    float* __restrict__ io,
    const float* __restrict__ g2, const float* __restrict__ b2,
    const __hip_bfloat16* __restrict__ w1t, const float* __restrict__ bm1,
    const __hip_bfloat16* __restrict__ w2t, const float* __restrict__ bm2)
{
    __shared__ __align__(16) char lds[65536];
    const int tid = threadIdx.x;
    const int lane = tid & 63, wid = tid >> 6;
    const long tok0 = (long)blockIdx.x * 64;
    const int col = lane & 15, kq = lane >> 4;
    const int n0 = wid * 64;

    {
        const float4 gv = *reinterpret_cast<const float4*>(g2 + lane * 4);
        const float4 bv = *reinterpret_cast<const float4*>(b2 + lane * 4);
        for (int tt = 0; tt < 16; ++tt) {
            const int r = wid * 16 + tt;
            const float4 v = *reinterpret_cast<const float4*>(io + (tok0 + r) * 256 + lane * 4);
            float s = v.x + v.y + v.z + v.w;
            float s2 = v.x * v.x + v.y * v.y + v.z * v.z + v.w * v.w;
            #pragma unroll
            for (int off = 32; off; off >>= 1) {
                s  += __shfl_xor(s,  off);
                s2 += __shfl_xor(s2, off);
            }
            const float mean = s * (1.f / 256.f);
            const float rs = rsqrtf(s2 * (1.f / 256.f) - mean * mean + 1e-5f);
            short4v o;
            o[0] = f2bf((v.x - mean) * rs * gv.x + bv.x);
            o[1] = f2bf((v.y - mean) * rs * gv.y + bv.y);
            o[2] = f2bf((v.z - mean) * rs * gv.z + bv.z);
            o[3] = f2bf((v.w - mean) * rs * gv.w + bv.w);
            const int addr = r * 512 + ((lane * 8) ^ ((r & 7) << 4));
            *reinterpret_cast<short4v*>(lds + addr) = o;
        }
    }
    __syncthreads();

    f32x4 accO[4][4];
    #pragma unroll
    for (int mt = 0; mt < 4; ++mt)
        #pragma unroll
        for (int nt = 0; nt < 4; ++nt) accO[mt][nt] = (f32x4){0.f, 0.f, 0.f, 0.f};

    for (int ch = 0; ch < 4; ++ch) {
        f32x4 accP[4][4];
        #pragma unroll
        for (int mt = 0; mt < 4; ++mt)
            #pragma unroll
            for (int nt = 0; nt < 4; ++nt) accP[mt][nt] = (f32x4){0.f, 0.f, 0.f, 0.f};

        #pragma unroll 2
        for (int ks = 0; ks < 8; ++ks) {
            short8v a[4], b[4];
            #pragma unroll
            for (int mt = 0; mt < 4; ++mt) {
                const int row = mt * 16 + col;
                const int byte = row * 512 + ((ks * 64 + kq * 16) ^ ((row & 7) << 4));
                a[mt] = *reinterpret_cast<const short8v*>(lds + byte);
            }
            #pragma unroll
            for (int nt = 0; nt < 4; ++nt) {
                const long ng = (long)(ch * 256 + n0 + nt * 16 + col);
                b[nt] = *reinterpret_cast<const short8v*>(
                    reinterpret_cast<const short*>(w1t) + ng * 256 + ks * 32 + kq * 8);
            }
            #pragma unroll
            for (int mt = 0; mt < 4; ++mt)
                #pragma unroll
                for (int nt = 0; nt < 4; ++nt)
                    accP[mt][nt] = __builtin_amdgcn_mfma_f32_16x16x32_bf16(
                        a[mt], b[nt], accP[mt][nt], 0, 0, 0);
        }

        __syncthreads();
        #pragma unroll
        for (int nt = 0; nt < 4; ++nt) {
            const float b1v = bm1[ch * 256 + n0 + nt * 16 + col];
            const int k2i = n0 + nt * 16 + col;
            #pragma unroll
            for (int mt = 0; mt < 4; ++mt) {
                #pragma unroll
                for (int r = 0; r < 4; ++r) {
                    float m = accP[mt][nt][r] + b1v;
                    m = 0.5f * m * (1.f + erff(m * 0.70710678118f));
                    const int row = mt * 16 + kq * 4 + r;
                    const int byte = 32768 + row * 512 + ((k2i * 2) ^ ((row & 7) << 4));
                    *reinterpret_cast<short*>(lds + byte) = f2bf(m);
                }
            }
        }
        __syncthreads();

        #pragma unroll 2
        for (int ks = 0; ks < 8; ++ks) {
            short8v a[4], b[4];
            #pragma unroll
            for (int mt = 0; mt < 4; ++mt) {
                const int row = mt * 16 + col;
                const int byte = 32768 + row * 512 + ((ks * 64 + kq * 16) ^ ((row & 7) << 4));
                a[mt] = *reinterpret_cast<const short8v*>(lds + byte);
            }
            #pragma unroll
            for (int nt = 0; nt < 4; ++nt) {
                const long ng = (long)(n0 + nt * 16 + col);
                b[nt] = *reinterpret_cast<const short8v*>(
                    reinterpret_cast<const short*>(w2t) + ng * 1024 + ch * 256 + ks * 32 + kq * 8);
            }
            #pragma unroll
            for (int mt = 0; mt < 4; ++mt)
                #pragma unroll
                for (int nt = 0; nt < 4; ++nt)
                    accO[mt][nt] = __builtin_amdgcn_mfma_f32_16x16x32_bf16(
                        a[mt], b[nt], accO[mt][nt], 0, 0, 0);
        }
    }

    #pragma unroll
    for (int nt = 0; nt < 4; ++nt) {
        const float b2v = bm2[n0 + nt * 16 + col];
        #pragma unroll
        for (int mt = 0; mt < 4; ++mt) {
            #pragma unroll
            for (int r = 0; r < 4; ++r) {
                const int row = mt * 16 + kq * 4 + r;
                const long idx = (tok0 + row) * 256 + n0 + nt * 16 + col;
                io[idx] = io[idx] + accO[mt][nt][r] + b2v;
            }
        }
    }
}

// ---------------------------------------------------------------------------
extern "C" void kernel_launch(void* const* d_in, const int* in_sizes, int n_in,
                              void* d_out, int out_size, void* d_ws, size_t ws_size,
                              hipStream_t stream)
{
    const float* fx   = (const float*)d_in[0];
    const float* ctx  = (const float*)d_in[1];
    const float* g1   = (const float*)d_in[2];
    const float* b1   = (const float*)d_in[3];
    const float* Wfx  = (const float*)d_in[4];
    const float* bfx  = (const float*)d_in[5];
    const float* Wx   = (const float*)d_in[6];
    const float* bx   = (const float*)d_in[7];
    const float* Wsl  = (const float*)d_in[8];
    const float* bsl  = (const float*)d_in[9];
    const float* temp = (const float*)d_in[10];
    const float* Wq   = (const float*)d_in[11];
    const float* Wk   = (const float*)d_in[12];
    const float* Wv   = (const float*)d_in[13];
    const float* Wcq  = (const float*)d_in[14];
    const float* bcq  = (const float*)d_in[15];
    const float* Wck  = (const float*)d_in[16];
    const float* bck  = (const float*)d_in[17];
    const float* Wcv  = (const float*)d_in[18];
    const float* bcv  = (const float*)d_in[19];
    const float* mix  = (const float*)d_in[20];
    const float* Wout = (const float*)d_in[21];
    const float* bout = (const float*)d_in[22];
    const float* g2   = (const float*)d_in[23];
    const float* b2   = (const float*)d_in[24];
    const float* Wm1  = (const float*)d_in[25];
    const float* bm1  = (const float*)d_in[26];
    const float* Wm2  = (const float*)d_in[27];
    const float* bm2  = (const float*)d_in[28];
    float* out = (float*)d_out;

    char* ws = (char*)d_ws;
    __hip_bfloat16* fxm  = (__hip_bfloat16*)ws;                         // 32MB
    __hip_bfloat16* sw   = (__hip_bfloat16*)(ws + (size_t)33554432);    // 32MB
    float* pst = (float*)(ws + (size_t)67108864);                       // 2MB  (512x1024 f32)
    float* pn  = (float*)(ws + (size_t)69206016);                       // 64KB (512x32 f32)
    __hip_bfloat16* ostT  = (__hip_bfloat16*)(ws + (size_t)69271552);   // 32KB [bh][d][g]
    __hip_bfloat16* wcat  = (__hip_bfloat16*)(ws + (size_t)69304320);   // 256KB [512][256]
    __hip_bfloat16* woutt = (__hip_bfloat16*)(ws + (size_t)69566464);   // 128KB [256][256]
    __hip_bfloat16* w1t   = (__hip_bfloat16*)(ws + (size_t)69697536);   // 512KB [1024][256]
    __hip_bfloat16* w2t   = (__hip_bfloat16*)(ws + (size_t)70221824);   // 512KB [256][1024]

    kconv_transpose<<<64,  256, 0, stream>>>(Wfx, wcat,          256, 256);
    kconv_transpose<<<64,  256, 0, stream>>>(Wx,  wcat + 65536,  256, 256);
    kconv_transpose<<<64,  256, 0, stream>>>(Wout, woutt,        256, 256);
    kconv_transpose<<<256, 256, 0, stream>>>(Wm1, w1t,           256, 1024);
    kconv_transpose<<<256, 256, 0, stream>>>(Wm2, w2t,           1024, 256);

    k1_mfma<<<1024, 256, 0, stream>>>(fx, g1, b1, wcat, bfx, bx, Wsl, bsl, temp,
                                      fxm, sw);
    k2_st_partial<<<512, 256, 0, stream>>>(fxm, sw, pst, pn);
    k3_slice_attn<<<16, 256, 0, stream>>>(pst, pn, ctx, Wq, Wk, Wv,
                                          Wcq, bcq, Wck, bck, Wcv, bcv, mix, ostT);
    k4_mfma<<<1024, 256, 0, stream>>>(sw, ostT, woutt, bout, fx, out);
    k5_mlp_mfma<<<1024, 256, 0, stream>>>(out, g2, b2, w1t, bm1, w2t, bm2);
}

// Round 4
// 432.045 us; speedup vs baseline: 7.7563x; 1.1709x over previous
//
#include <hip/hip_runtime.h>
#include <hip/hip_bf16.h>

#define BATCH 2
#define NTOK  32768
#define CH    256
#define NH    8
#define HDIM  32
#define NG    32
#define NSC   64
#define NDC   32

typedef __attribute__((ext_vector_type(8))) short short8v;
typedef __attribute__((ext_vector_type(4))) short short4v;
typedef __attribute__((ext_vector_type(4))) float f32x4;

static __device__ __forceinline__ short f2bf(float f) {
    __hip_bfloat16 h = __float2bfloat16(f);
    return __builtin_bit_cast(short, h);
}
static __device__ __forceinline__ float bf2f(short s) {
    return __bfloat162float(__builtin_bit_cast(__hip_bfloat16, s));
}

// ---------------------------------------------------------------------------
// Weight transpose+convert: in f32 [K][N] -> out bf16 [N][K].
// ---------------------------------------------------------------------------
__global__ __launch_bounds__(256) void kconv_transpose(
    const float* __restrict__ in, __hip_bfloat16* __restrict__ out,
    int K, int N)
{
    __shared__ float t[32][33];
    const int nb = N >> 5;
    const int bk = blockIdx.x / nb;
    const int bn = blockIdx.x % nb;
    const int c = threadIdx.x & 31, r0 = threadIdx.x >> 5;
    #pragma unroll
    for (int i = 0; i < 4; ++i) {
        const int r = r0 + i * 8;
        t[r][c] = in[(long)(bk * 32 + r) * N + bn * 32 + c];
    }
    __syncthreads();
    #pragma unroll
    for (int i = 0; i < 4; ++i) {
        const int r = r0 + i * 8;
        out[(long)(bn * 32 + r) * K + bk * 32 + c] = __float2bfloat16(t[c][r]);
    }
}

// ---------------------------------------------------------------------------
// Kernel 1 (MFMA): LN1 + dual GEMM (x@[Wfx|Wx]) + slice softmax.
// ---------------------------------------------------------------------------
__global__ __launch_bounds__(256, 2) void k1_mfma(
    const float* __restrict__ fx,
    const float* __restrict__ g1, const float* __restrict__ b1,
    const __hip_bfloat16* __restrict__ wcat,   // [512][256] = [Wfx^T ; Wx^T]
    const float* __restrict__ bfx, const float* __restrict__ bx,
    const float* __restrict__ Wsl, const float* __restrict__ bsl,
    const float* __restrict__ temp,
    __hip_bfloat16* __restrict__ fxm_o, __hip_bfloat16* __restrict__ sw_o)
{
    __shared__ __align__(16) char lds[65536];
    const int tid = threadIdx.x;
    const int lane = tid & 63, wid = tid >> 6;
    const long tok0 = (long)blockIdx.x * 64;
    const int col = lane & 15, kq = lane >> 4;

    {
        const float4 gv = *reinterpret_cast<const float4*>(g1 + lane * 4);
        const float4 bv = *reinterpret_cast<const float4*>(b1 + lane * 4);
        for (int tt = 0; tt < 16; ++tt) {
            const int r = wid * 16 + tt;
            const float4 v = *reinterpret_cast<const float4*>(fx + (tok0 + r) * 256 + lane * 4);
            float s = v.x + v.y + v.z + v.w;
            float s2 = v.x * v.x + v.y * v.y + v.z * v.z + v.w * v.w;
            #pragma unroll
            for (int off = 32; off; off >>= 1) {
                s  += __shfl_xor(s,  off);
                s2 += __shfl_xor(s2, off);
            }
            const float mean = s * (1.f / 256.f);
            const float rs = rsqrtf(s2 * (1.f / 256.f) - mean * mean + 1e-5f);
            short4v o;
            o[0] = f2bf((v.x - mean) * rs * gv.x + bv.x);
            o[1] = f2bf((v.y - mean) * rs * gv.y + bv.y);
            o[2] = f2bf((v.z - mean) * rs * gv.z + bv.z);
            o[3] = f2bf((v.w - mean) * rs * gv.w + bv.w);
            const int addr = r * 512 + ((lane * 8) ^ ((r & 7) << 4));
            *reinterpret_cast<short4v*>(lds + addr) = o;
        }
    }
    __syncthreads();

    f32x4 acc[4][8];
    #pragma unroll
    for (int mt = 0; mt < 4; ++mt)
        #pragma unroll
        for (int nt = 0; nt < 8; ++nt) acc[mt][nt] = (f32x4){0.f, 0.f, 0.f, 0.f};

    for (int ks = 0; ks < 8; ++ks) {
        short8v a[4];
        #pragma unroll
        for (int mt = 0; mt < 4; ++mt) {
            const int row = mt * 16 + col;
            const int byte = row * 512 + ((ks * 64 + kq * 16) ^ ((row & 7) << 4));
            a[mt] = *reinterpret_cast<const short8v*>(lds + byte);
        }
        #pragma unroll
        for (int nt = 0; nt < 8; ++nt) {
            const long ng = (long)(wid * 128 + nt * 16 + col);
            const short8v b = *reinterpret_cast<const short8v*>(
                reinterpret_cast<const short*>(wcat) + ng * 256 + ks * 32 + kq * 8);
            #pragma unroll
            for (int mt = 0; mt < 4; ++mt)
                acc[mt][nt] = __builtin_amdgcn_mfma_f32_16x16x32_bf16(
                    a[mt], b, acc[mt][nt], 0, 0, 0);
        }
    }
    __syncthreads();

    #pragma unroll
    for (int nt = 0; nt < 8; ++nt) {
        const int c = wid * 128 + nt * 16 + col;
        const float bb = (c < 256) ? bfx[c] : bx[c - 256];
        #pragma unroll
        for (int mt = 0; mt < 4; ++mt) {
            #pragma unroll
            for (int r = 0; r < 4; ++r) {
                const int row = mt * 16 + kq * 4 + r;
                const int byte = row * 1024 + ((c * 2) ^ ((row & 7) << 4));
                *reinterpret_cast<short*>(lds + byte) = f2bf(acc[mt][nt][r] + bb);
            }
        }
    }
    __syncthreads();

    #pragma unroll
    for (int it = 0; it < 8; ++it) {
        const int idx = it * 256 + tid;
        const int row = idx >> 5, ch = idx & 31;
        const short8v val = *reinterpret_cast<const short8v*>(
            lds + row * 1024 + ((ch * 16) ^ ((row & 7) << 4)));
        *reinterpret_cast<short8v*>(
            reinterpret_cast<short*>(fxm_o) + (tok0 + row) * 256 + ch * 8) = val;
    }

    #pragma unroll
    for (int pp = 0; pp < 2; ++pp) {
        const int p = pp * 256 + tid;
        const int t = p >> 3, h = p & 7;
        float xm[32];
        #pragma unroll
        for (int d = 0; d < 32; ++d) {
            const int byte = t * 1024 + (((256 + h * 32 + d) * 2) ^ ((t & 7) << 4));
            xm[d] = bf2f(*reinterpret_cast<const short*>(lds + byte));
        }
        float lg[32];
        #pragma unroll
        for (int g = 0; g < 32; ++g) lg[g] = bsl[g];
        for (int d = 0; d < 32; ++d) {
            const float xd = xm[d];
            #pragma unroll
            for (int g4 = 0; g4 < 8; ++g4) {
                const float4 w = *reinterpret_cast<const float4*>(Wsl + d * 32 + g4 * 4);
                lg[g4 * 4 + 0] += xd * w.x;
                lg[g4 * 4 + 1] += xd * w.y;
                lg[g4 * 4 + 2] += xd * w.z;
                lg[g4 * 4 + 3] += xd * w.w;
            }
        }
        const float it_ = 1.f / temp[h];
        float mx = -1e30f;
        #pragma unroll
        for (int g = 0; g < 32; ++g) { lg[g] *= it_; mx = fmaxf(mx, lg[g]); }
        float ssum = 0.f;
        #pragma unroll
        for (int g = 0; g < 32; ++g) { lg[g] = expf(lg[g] - mx); ssum += lg[g]; }
        const float inv = 1.f / ssum;
        __hip_bfloat16* swp = sw_o + (tok0 + t) * 256 + h * 32;
        #pragma unroll
        for (int g = 0; g < 32; ++g) swp[g] = __float2bfloat16(lg[g] * inv);
    }
}

// ---------------------------------------------------------------------------
// Kernel 2: st partials.
// ---------------------------------------------------------------------------
__global__ __launch_bounds__(256) void k2_st_partial(
    const __hip_bfloat16* __restrict__ fxm, const __hip_bfloat16* __restrict__ sw,
    float* __restrict__ pst, float* __restrict__ pn)
{
    __shared__ float fl[32][32];
    __shared__ float sl[32][32];
    const int tid = threadIdx.x;
    const int blk = blockIdx.x;
    const int bh = blk >> 5, chunk = blk & 31;
    const int b = bh >> 3, h = bh & 7;
    const long nbase = (long)b * NTOK + (long)chunk * 1024;
    const int g = tid >> 3, dq = tid & 7, db = dq * 4;
    const int lr = tid >> 3, lc4 = (tid & 7) * 4;
    float a0 = 0.f, a1 = 0.f, a2 = 0.f, a3 = 0.f, nacc = 0.f;

    for (int nb = 0; nb < 1024; nb += 32) {
        const long base = (nbase + nb + lr) * 256 + h * 32 + lc4;
        const short4v fv = *reinterpret_cast<const short4v*>(
            reinterpret_cast<const short*>(fxm) + base);
        const short4v sv = *reinterpret_cast<const short4v*>(
            reinterpret_cast<const short*>(sw) + base);
        float4 ff, sf;
        ff.x = bf2f(fv[0]); ff.y = bf2f(fv[1]); ff.z = bf2f(fv[2]); ff.w = bf2f(fv[3]);
        sf.x = bf2f(sv[0]); sf.y = bf2f(sv[1]); sf.z = bf2f(sv[2]); sf.w = bf2f(sv[3]);
        __syncthreads();
        *reinterpret_cast<float4*>(&fl[lr][lc4]) = ff;
        *reinterpret_cast<float4*>(&sl[lr][lc4]) = sf;
        __syncthreads();
        #pragma unroll
        for (int t = 0; t < 32; ++t) {
            const float s = sl[t][g];
            if (dq == 0) nacc += s;
            a0 += s * fl[t][db + 0];
            a1 += s * fl[t][db + 1];
            a2 += s * fl[t][db + 2];
            a3 += s * fl[t][db + 3];
        }
    }
    float* o = pst + (long)blk * 1024 + g * 32 + db;
    o[0] = a0; o[1] = a1; o[2] = a2; o[3] = a3;
    if (dq == 0) pn[blk * 32 + g] = nacc;
}

// ---------------------------------------------------------------------------
// Kernel 3: reduce partials -> st; slice self-attn + cross-attn -> ostT (bf16).
// ---------------------------------------------------------------------------
__global__ __launch_bounds__(256) void k3_slice_attn(
    const float* __restrict__ pst, const float* __restrict__ pn,
    const float* __restrict__ ctx,
    const float* __restrict__ Wq, const float* __restrict__ Wk, const float* __restrict__ Wv,
    const float* __restrict__ Wcq, const float* __restrict__ bcq,
    const float* __restrict__ Wck, const float* __restrict__ bck,
    const float* __restrict__ Wcv, const float* __restrict__ bcv,
    const float* __restrict__ mix, __hip_bfloat16* __restrict__ ostT_o)
{
    __shared__ float st[1024], qm[1024], km[1024], vm[1024], cqm[1024];
    __shared__ float ckm[2048], cvm[2048], attn[2048], stok[1024], nb[32];
    const int tid = threadIdx.x;
    const int bh = blockIdx.x;

    if (tid < 32) {
        float s = 0.f;
        for (int c = 0; c < 32; ++c) s += pn[(bh * 32 + c) * 32 + tid];
        nb[tid] = s;
    }
    __syncthreads();
    for (int i = tid; i < 1024; i += 256) {
        float s = 0.f;
        for (int c = 0; c < 32; ++c) s += pst[(long)(bh * 32 + c) * 1024 + i];
        st[i] = s / (nb[i >> 5] + 1e-5f);
    }
    __syncthreads();

    for (int i = tid; i < 1024; i += 256) {
        const int g = i >> 5, d = i & 31;
        float aq = 0.f, ak = 0.f, av = 0.f, ac = bcq[d];
        #pragma unroll
        for (int e = 0; e < 32; ++e) {
            const float s = st[g * 32 + e];
            aq += s * Wq[e * 32 + d];
            ak += s * Wk[e * 32 + d];
            av += s * Wv[e * 32 + d];
            ac += s * Wcq[e * 32 + d];
        }
        qm[i] = aq; km[i] = ak; vm[i] = av; cqm[i] = ac;
    }
    const float* cbp = ctx + (long)bh * (NSC * NDC);
    for (int i = tid; i < 2048; i += 256) {
        const int s_ = i >> 5, d = i & 31;
        float w1 = bck[d], w2 = bcv[d];
        #pragma unroll
        for (int e = 0; e < 32; ++e) {
            const float cval = cbp[s_ * 32 + e];
            w1 += cval * Wck[e * 32 + d];
            w2 += cval * Wcv[e * 32 + d];
        }
        ckm[i] = w1; cvm[i] = w2;
    }
    __syncthreads();

    const float scale = 0.17677669529663687f;
    for (int i = tid; i < 1024; i += 256) {
        const int g = i >> 5, m = i & 31;
        float a = 0.f;
        #pragma unroll
        for (int d = 0; d < 32; ++d) a += qm[g * 32 + d] * km[m * 32 + d];
        attn[i] = a * scale;
    }
    __syncthreads();
    if (tid < 32) {
        float mx = -1e30f;
        for (int m = 0; m < 32; ++m) mx = fmaxf(mx, attn[tid * 32 + m]);
        float s = 0.f;
        for (int m = 0; m < 32; ++m) { const float e = expf(attn[tid * 32 + m] - mx); attn[tid * 32 + m] = e; s += e; }
        const float inv = 1.f / s;
        for (int m = 0; m < 32; ++m) attn[tid * 32 + m] *= inv;
    }
    __syncthreads();
    for (int i = tid; i < 1024; i += 256) {
        const int g = i >> 5, d = i & 31;
        float a = 0.f;
        #pragma unroll
        for (int m = 0; m < 32; ++m) a += attn[g * 32 + m] * vm[m * 32 + d];
        stok[i] = a;
    }
    __syncthreads();
    for (int i = tid; i < 2048; i += 256) {
        const int g = i >> 6, s_ = i & 63;
        float a = 0.f;
        #pragma unroll
        for (int d = 0; d < 32; ++d) a += cqm[g * 32 + d] * ckm[s_ * 32 + d];
        attn[i] = a * scale;
    }
    __syncthreads();
    if (tid < 32) {
        float mx = -1e30f;
        for (int m = 0; m < 64; ++m) mx = fmaxf(mx, attn[tid * 64 + m]);
        float s = 0.f;
        for (int m = 0; m < 64; ++m) { const float e = expf(attn[tid * 64 + m] - mx); attn[tid * 64 + m] = e; s += e; }
        const float inv = 1.f / s;
        for (int m = 0; m < 64; ++m) attn[tid * 64 + m] *= inv;
    }
    __syncthreads();
    const float mw = 1.f / (1.f + expf(-mix[0]));
    for (int i = tid; i < 1024; i += 256) {
        const int g = i >> 5, d = i & 31;
        float a = 0.f;
        #pragma unroll
        for (int s_ = 0; s_ < 64; ++s_) a += attn[g * 64 + s_] * cvm[s_ * 32 + d];
        const float val = mw * stok[i] + (1.f - mw) * a;
        ostT_o[(long)bh * 1024 + d * 32 + g] = __float2bfloat16(val);
    }
}

// ---------------------------------------------------------------------------
// Kernel 4 (MFMA): de-slice + Wout GEMM + residual.
// ---------------------------------------------------------------------------
__global__ __launch_bounds__(256, 2) void k4_mfma(
    const __hip_bfloat16* __restrict__ sw, const __hip_bfloat16* __restrict__ ostT,
    const __hip_bfloat16* __restrict__ woutt, const float* __restrict__ bout,
    const float* __restrict__ fx, float* __restrict__ out)
{
    __shared__ __align__(16) char lds[65536];
    const int tid = threadIdx.x;
    const int lane = tid & 63, wid = tid >> 6;
    const long tok0 = (long)blockIdx.x * 64;
    const int b = (int)(tok0 >> 15);
    const int col = lane & 15, kq = lane >> 4;

    #pragma unroll
    for (int it = 0; it < 8; ++it) {
        const int idx = it * 256 + tid;
        const int row = idx >> 5, ch = idx & 31;
        const short8v val = *reinterpret_cast<const short8v*>(
            reinterpret_cast<const short*>(sw) + (tok0 + row) * 256 + ch * 8);
        *reinterpret_cast<short8v*>(lds + row * 512 + ((ch * 16) ^ ((row & 7) << 4))) = val;
    }
    __syncthreads();

    f32x4 accal[2][4][2];
    #pragma unroll
    for (int hh = 0; hh < 2; ++hh) {
        const int h = wid * 2 + hh;
        short8v a[4];
        #pragma unroll
        for (int mt = 0; mt < 4; ++mt) {
            const int row = mt * 16 + col;
            const int byte = row * 512 + (((h * 32 + kq * 8) * 2) ^ ((row & 7) << 4));
            a[mt] = *reinterpret_cast<const short8v*>(lds + byte);
        }
        #pragma unroll
        for (int nt = 0; nt < 2; ++nt) {
            const int d = nt * 16 + col;
            const short8v bfr = *reinterpret_cast<const short8v*>(
                reinterpret_cast<const short*>(ostT) + ((b * 8 + h) * 32 + d) * 32 + kq * 8);
            #pragma unroll
            for (int mt = 0; mt < 4; ++mt) {
                accal[hh][mt][nt] = (f32x4){0.f, 0.f, 0.f, 0.f};
                accal[hh][mt][nt] = __builtin_amdgcn_mfma_f32_16x16x32_bf16(
                    a[mt], bfr, accal[hh][mt][nt], 0, 0, 0);
            }
        }
    }
    #pragma unroll
    for (int hh = 0; hh < 2; ++hh) {
        const int h = wid * 2 + hh;
        #pragma unroll
        for (int nt = 0; nt < 2; ++nt) {
            const int cc = h * 32 + nt * 16 + col;
            #pragma unroll
            for (int mt = 0; mt < 4; ++mt) {
                #pragma unroll
                for (int r = 0; r < 4; ++r) {
                    const int row = mt * 16 + kq * 4 + r;
                    const int byte = 32768 + row * 512 + ((cc * 2) ^ ((row & 7) << 4));
                    *reinterpret_cast<short*>(lds + byte) = f2bf(accal[hh][mt][nt][r]);
                }
            }
        }
    }
    __syncthreads();

    f32x4 acc[4][4];
    #pragma unroll
    for (int mt = 0; mt < 4; ++mt)
        #pragma unroll
        for (int nt = 0; nt < 4; ++nt) acc[mt][nt] = (f32x4){0.f, 0.f, 0.f, 0.f};

    for (int ks = 0; ks < 8; ++ks) {
        short8v a[4];
        #pragma unroll
        for (int mt = 0; mt < 4; ++mt) {
            const int row = mt * 16 + col;
            const int byte = 32768 + row * 512 + ((ks * 64 + kq * 16) ^ ((row & 7) << 4));
            a[mt] = *reinterpret_cast<const short8v*>(lds + byte);
        }
        #pragma unroll
        for (int nt = 0; nt < 4; ++nt) {
            const long ng = (long)(wid * 64 + nt * 16 + col);
            const short8v bfr = *reinterpret_cast<const short8v*>(
                reinterpret_cast<const short*>(woutt) + ng * 256 + ks * 32 + kq * 8);
            #pragma unroll
            for (int mt = 0; mt < 4; ++mt)
                acc[mt][nt] = __builtin_amdgcn_mfma_f32_16x16x32_bf16(
                    a[mt], bfr, acc[mt][nt], 0, 0, 0);
        }
    }

    #pragma unroll
    for (int nt = 0; nt < 4; ++nt) {
        const int c = wid * 64 + nt * 16 + col;
        const float bb = bout[c];
        #pragma unroll
        for (int mt = 0; mt < 4; ++mt) {
            #pragma unroll
            for (int r = 0; r < 4; ++r) {
                const int row = mt * 16 + kq * 4 + r;
                const long idx = (tok0 + row) * 256 + c;
                out[idx] = acc[mt][nt][r] + bb + fx[idx];
            }
        }
    }
}

// ---------------------------------------------------------------------------
// Kernel 5 (MFMA, 8 waves): fused MLP. 64 tokens/block, 512 threads.
// Wave w owns n-slice of 32 (both hidden-chunk cols and output cols).
// GELU: tanh approximation via v_exp/v_rcp.
// ---------------------------------------------------------------------------
__global__ __launch_bounds__(512, 4) void k5_mlp_mfma(
    float* __restrict__ io,
    const float* __restrict__ g2, const float* __restrict__ b2,
    const __hip_bfloat16* __restrict__ w1t, const float* __restrict__ bm1,
    const __hip_bfloat16* __restrict__ w2t, const float* __restrict__ bm2)
{
    __shared__ __align__(16) char lds[65536];   // [0,32K): A  [32K,64K): A2
    const int tid = threadIdx.x;
    const int lane = tid & 63, wid = tid >> 6;   // wid 0..7
    const long tok0 = (long)blockIdx.x * 64;
    const int col = lane & 15, kq = lane >> 4;
    const int n0 = wid * 32;

    // ---- LN2 -> A (bf16, swizzled). Each wave: 8 tokens. ----
    {
        const float4 gv = *reinterpret_cast<const float4*>(g2 + lane * 4);
        const float4 bv = *reinterpret_cast<const float4*>(b2 + lane * 4);
        #pragma unroll
        for (int tt = 0; tt < 8; ++tt) {
            const int r = wid * 8 + tt;
            const float4 v = *reinterpret_cast<const float4*>(io + (tok0 + r) * 256 + lane * 4);
            float s = v.x + v.y + v.z + v.w;
            float s2 = v.x * v.x + v.y * v.y + v.z * v.z + v.w * v.w;
            #pragma unroll
            for (int off = 32; off; off >>= 1) {
                s  += __shfl_xor(s,  off);
                s2 += __shfl_xor(s2, off);
            }
            const float mean = s * (1.f / 256.f);
            const float rs = rsqrtf(s2 * (1.f / 256.f) - mean * mean + 1e-5f);
            short4v o;
            o[0] = f2bf((v.x - mean) * rs * gv.x + bv.x);
            o[1] = f2bf((v.y - mean) * rs * gv.y + bv.y);
            o[2] = f2bf((v.z - mean) * rs * gv.z + bv.z);
            o[3] = f2bf((v.w - mean) * rs * gv.w + bv.w);
            const int addr = r * 512 + ((lane * 8) ^ ((r & 7) << 4));
            *reinterpret_cast<short4v*>(lds + addr) = o;
        }
    }
    __syncthreads();

    f32x4 accO[4][2];
    #pragma unroll
    for (int mt = 0; mt < 4; ++mt)
        #pragma unroll
        for (int nt = 0; nt < 2; ++nt) accO[mt][nt] = (f32x4){0.f, 0.f, 0.f, 0.f};

    for (int ch = 0; ch < 4; ++ch) {
        // ---- GEMM1: P(64 x 32) = A @ W1[:, ch*256 + n0 .. +32] ----
        f32x4 accP[4][2];
        #pragma unroll
        for (int mt = 0; mt < 4; ++mt)
            #pragma unroll
            for (int nt = 0; nt < 2; ++nt) accP[mt][nt] = (f32x4){0.f, 0.f, 0.f, 0.f};

        #pragma unroll 2
        for (int ks = 0; ks < 8; ++ks) {
            short8v a[4], b[2];
            #pragma unroll
            for (int mt = 0; mt < 4; ++mt) {
                const int row = mt * 16 + col;
                const int byte = row * 512 + ((ks * 64 + kq * 16) ^ ((row & 7) << 4));
                a[mt] = *reinterpret_cast<const short8v*>(lds + byte);
            }
            #pragma unroll
            for (int nt = 0; nt < 2; ++nt) {
                const long ng = (long)(ch * 256 + n0 + nt * 16 + col);
                b[nt] = *reinterpret_cast<const short8v*>(
                    reinterpret_cast<const short*>(w1t) + ng * 256 + ks * 32 + kq * 8);
            }
            #pragma unroll
            for (int mt = 0; mt < 4; ++mt)
                #pragma unroll
                for (int nt = 0; nt < 2; ++nt)
                    accP[mt][nt] = __builtin_amdgcn_mfma_f32_16x16x32_bf16(
                        a[mt], b[nt], accP[mt][nt], 0, 0, 0);
        }

        // ---- bias + fast GELU -> A2 (bf16, swizzled) ----
        __syncthreads();   // waves done reading A2 of previous chunk
        #pragma unroll
        for (int nt = 0; nt < 2; ++nt) {
            const float b1v = bm1[ch * 256 + n0 + nt * 16 + col];
            const int k2i = n0 + nt * 16 + col;
            #pragma unroll
            for (int mt = 0; mt < 4; ++mt) {
                #pragma unroll
                for (int r = 0; r < 4; ++r) {
                    float m = accP[mt][nt][r] + b1v;
                    // gelu(m) ~= m * sigmoid(1.5957692*(m + 0.044715 m^3))
                    const float u = __builtin_fmaf(0.044715f * m, m * m, m);
                    const float e = __expf(-1.5957691216057308f * u);
                    m = m * __builtin_amdgcn_rcpf(1.f + e);
                    const int row = mt * 16 + kq * 4 + r;
                    const int byte = 32768 + row * 512 + ((k2i * 2) ^ ((row & 7) << 4));
                    *reinterpret_cast<short*>(lds + byte) = f2bf(m);
                }
            }
        }
        __syncthreads();

        // ---- GEMM2: accO += A2 @ W2[ch*256.., n0..n0+32] ----
        #pragma unroll 2
        for (int ks = 0; ks < 8; ++ks) {
            short8v a[4], b[2];
            #pragma unroll
            for (int mt = 0; mt < 4; ++mt) {
                const int row = mt * 16 + col;
                const int byte = 32768 + row * 512 + ((ks * 64 + kq * 16) ^ ((row & 7) << 4));
                a[mt] = *reinterpret_cast<const short8v*>(lds + byte);
            }
            #pragma unroll
            for (int nt = 0; nt < 2; ++nt) {
                const long ng = (long)(n0 + nt * 16 + col);
                b[nt] = *reinterpret_cast<const short8v*>(
                    reinterpret_cast<const short*>(w2t) + ng * 1024 + ch * 256 + ks * 32 + kq * 8);
            }
            #pragma unroll
            for (int mt = 0; mt < 4; ++mt)
                #pragma unroll
                for (int nt = 0; nt < 2; ++nt)
                    accO[mt][nt] = __builtin_amdgcn_mfma_f32_16x16x32_bf16(
                        a[mt], b[nt], accO[mt][nt], 0, 0, 0);
        }
    }

    // ---- epilogue: bias + residual + store ----
    #pragma unroll
    for (int nt = 0; nt < 2; ++nt) {
        const int c = n0 + nt * 16 + col;
        const float b2v = bm2[c];
        #pragma unroll
        for (int mt = 0; mt < 4; ++mt) {
            #pragma unroll
            for (int r = 0; r < 4; ++r) {
                const int row = mt * 16 + kq * 4 + r;
                const long idx = (tok0 + row) * 256 + c;
                io[idx] = io[idx] + accO[mt][nt][r] + b2v;
            }
        }
    }
}

// ---------------------------------------------------------------------------
extern "C" void kernel_launch(void* const* d_in, const int* in_sizes, int n_in,
                              void* d_out, int out_size, void* d_ws, size_t ws_size,
                              hipStream_t stream)
{
    const float* fx   = (const float*)d_in[0];
    const float* ctx  = (const float*)d_in[1];
    const float* g1   = (const float*)d_in[2];
    const float* b1   = (const float*)d_in[3];
    const float* Wfx  = (const float*)d_in[4];
    const float* bfx  = (const float*)d_in[5];
    const float* Wx   = (const float*)d_in[6];
    const float* bx   = (const float*)d_in[7];
    const float* Wsl  = (const float*)d_in[8];
    const float* bsl  = (const float*)d_in[9];
    const float* temp = (const float*)d_in[10];
    const float* Wq   = (const float*)d_in[11];
    const float* Wk   = (const float*)d_in[12];
    const float* Wv   = (const float*)d_in[13];
    const float* Wcq  = (const float*)d_in[14];
    const float* bcq  = (const float*)d_in[15];
    const float* Wck  = (const float*)d_in[16];
    const float* bck  = (const float*)d_in[17];
    const float* Wcv  = (const float*)d_in[18];
    const float* bcv  = (const float*)d_in[19];
    const float* mix  = (const float*)d_in[20];
    const float* Wout = (const float*)d_in[21];
    const float* bout = (const float*)d_in[22];
    const float* g2   = (const float*)d_in[23];
    const float* b2   = (const float*)d_in[24];
    const float* Wm1  = (const float*)d_in[25];
    const float* bm1  = (const float*)d_in[26];
    const float* Wm2  = (const float*)d_in[27];
    const float* bm2  = (const float*)d_in[28];
    float* out = (float*)d_out;

    char* ws = (char*)d_ws;
    __hip_bfloat16* fxm  = (__hip_bfloat16*)ws;                         // 32MB
    __hip_bfloat16* sw   = (__hip_bfloat16*)(ws + (size_t)33554432);    // 32MB
    float* pst = (float*)(ws + (size_t)67108864);                       // 2MB
    float* pn  = (float*)(ws + (size_t)69206016);                       // 64KB
    __hip_bfloat16* ostT  = (__hip_bfloat16*)(ws + (size_t)69271552);   // 32KB
    __hip_bfloat16* wcat  = (__hip_bfloat16*)(ws + (size_t)69304320);   // 256KB
    __hip_bfloat16* woutt = (__hip_bfloat16*)(ws + (size_t)69566464);   // 128KB
    __hip_bfloat16* w1t   = (__hip_bfloat16*)(ws + (size_t)69697536);   // 512KB
    __hip_bfloat16* w2t   = (__hip_bfloat16*)(ws + (size_t)70221824);   // 512KB

    kconv_transpose<<<64,  256, 0, stream>>>(Wfx, wcat,          256, 256);
    kconv_transpose<<<64,  256, 0, stream>>>(Wx,  wcat + 65536,  256, 256);
    kconv_transpose<<<64,  256, 0, stream>>>(Wout, woutt,        256, 256);
    kconv_transpose<<<256, 256, 0, stream>>>(Wm1, w1t,           256, 1024);
    kconv_transpose<<<256, 256, 0, stream>>>(Wm2, w2t,           1024, 256);

    k1_mfma<<<1024, 256, 0, stream>>>(fx, g1, b1, wcat, bfx, bx, Wsl, bsl, temp,
                                      fxm, sw);
    k2_st_partial<<<512, 256, 0, stream>>>(fxm, sw, pst, pn);
    k3_slice_attn<<<16, 256, 0, stream>>>(pst, pn, ctx, Wq, Wk, Wv,
                                          Wcq, bcq, Wck, bck, Wcv, bcv, mix, ostT);
    k4_mfma<<<1024, 256, 0, stream>>>(sw, ostT, woutt, bout, fx, out);
    k5_mlp_mfma<<<1024, 512, 0, stream>>>(out, g2, b2, w1t, bm1, w2t, bm2);
}